// Round 9
// baseline (882.687 us; speedup 1.0000x reference)
//
#include <hip/hip_runtime.h>

constexpr double PI2 = 6.283185307179586476925286766559;
constexpr float INV_HW = 1.0f / 65536.0f;

// B=16, D=32, H=W=256, M=12, L=4
// ws (floats), total 37,290,560 (142.25 MiB — proven safe):
//   cs[512] | z[33554432] | gy[3145728] | fc[294912] | fm[294912] | bn[64]
//   gx ALIASES z[0:3145728]; part (262144) ALIASES fc.
// gx layout: [b][y][ch32][mode24] (mode = 2*kx+comp) — block-contiguous writes.

__global__ __launch_bounds__(256) void k_init(float* __restrict__ cs) {
  int t = threadIdx.x;
  double a = PI2 * (double)t / 256.0;
  cs[2*t]   = (float)cos(a);
  cs[2*t+1] = (float)sin(a);
}

// Layer-0: h0 in registers -> x-DFT to 12 modes -> gx[b][y][ch][24]
__global__ __launch_bounds__(256) void k_embed_fwd(
    const float* __restrict__ xin, const float* __restrict__ coords,
    const float* __restrict__ w_in, const float* __restrict__ b_in,
    const float* __restrict__ cs, float* __restrict__ gxo)
{
  __shared__ float wl[96], bl[32];
  __shared__ __align__(16) float csl[512];
  __shared__ float S[32*257];
  const int tid = threadIdx.x;
  if (tid < 96) wl[tid] = w_in[tid];
  if (tid >= 96 && tid < 128) bl[tid-96] = b_in[tid-96];
  for (int f = tid; f < 512; f += 256) csl[f] = cs[f];
  const int b = blockIdx.x >> 8, y = blockIdx.x & 255;
  const float xv = xin[(b*256 + y)*256 + tid];
  const float c0 = coords[y*256 + tid];
  const float c1 = coords[65536 + y*256 + tid];
  __syncthreads();
  #pragma unroll 8
  for (int d = 0; d < 32; ++d)
    S[d*257 + tid] = wl[3*d]*xv + wl[3*d+1]*c0 + wl[3*d+2]*c1 + bl[d];
  __syncthreads();
  const int task = tid >> 5, o = tid & 31;
  if (task < 6) {
    const int kx0 = task*2, kx1 = kx0 + 1;
    float ar0=0.f, ai0=0.f, ar1=0.f, ai1=0.f;
    const float* Sp = &S[o*257];
    int t0 = 0, t1 = 0;
    for (int xx = 0; xx < 256; ++xx) {
      float v = Sp[xx];
      float2 w0 = *(const float2*)&csl[2*t0];
      float2 w1 = *(const float2*)&csl[2*t1];
      ar0 += v*w0.x; ai0 -= v*w0.y;
      ar1 += v*w1.x; ai1 -= v*w1.y;
      t0 = (t0 + kx0) & 255;
      t1 = (t1 + kx1) & 255;
    }
    float4 w4; w4.x = ar0; w4.y = ai0; w4.z = ar1; w4.w = ai1;
    *(float4*)(gxo + ((long)(b*256 + y)*32 + o)*24 + task*4) = w4;
  }
}

// Forward DFT along y with BN-affine fold on staging.
// Reads gx[b][y][ch][mode]; fc layout [b][ky24][kx12][C32][2]
__global__ __launch_bounds__(256) void k_fwd_y(
    const float* __restrict__ gx, const float* __restrict__ cs,
    const float* __restrict__ bnp, float* __restrict__ fc)
{
  __shared__ __align__(16) float R[8*528];
  __shared__ __align__(16) float csl[512];
  const int tid = threadIdx.x;
  for (int f = tid; f < 512; f += 256) csl[f] = cs[f];
  const int g = tid >> 5, s = tid & 31;
  const int task = blockIdx.x*8 + g;        // [0, 6144)
  const int bc = task / 12, kx = task % 12;
  const int bb = bc >> 5, ch = bc & 31;
  {
    const float* rr = gx + ((long)(bb*256)*32 + ch)*24 + 2*kx;  // + y*768
    float sc = 1.0f, badd = 0.0f;
    if (bnp) {
      sc = bnp[ch];
      badd = (kx == 0) ? 256.0f*bnp[32 + ch] : 0.0f;
    }
    for (int i = 0; i < 8; ++i) {          // 32 lanes x 8 = 256 y
      int y = s + 32*i;
      float2 v = *(const float2*)(rr + (long)y*768);
      R[g*528 + 2*y]     = sc*v.x + badd;
      R[g*528 + 2*y + 1] = sc*v.y;
    }
  }
  __syncthreads();
  if (s < 24) {
    const int kyv = (s < 12) ? s : (232 + s);
    float ar = 0.f, ai = 0.f;
    int tt = 0;
    const float* Rg = &R[g*528];
    for (int y = 0; y < 256; ++y) {
      float2 v = *(const float2*)&Rg[2*y];
      float2 w = *(const float2*)&csl[2*tt];
      ar += v.x*w.x + v.y*w.y;      // v * conj(e^{i theta})
      ai += v.y*w.x - v.x*w.y;
      tt = (tt + kyv) & 255;
    }
    float* o = fc + ((bb*24 + s)*12 + kx)*64 + 2*ch;
    o[0] = ar; o[1] = ai;
  }
}

// Per-mode complex channel mix: out[b,o] = sum_i fin[b,i] * w[i,o]
__global__ __launch_bounds__(256) void k_mix(
    const float* __restrict__ fc, float* __restrict__ fm,
    const float* __restrict__ w1r, const float* __restrict__ w1i,
    const float* __restrict__ w2r, const float* __restrict__ w2i)
{
  const int ky = blockIdx.x / 12, kx = blockIdx.x % 12;
  const int tid = threadIdx.x;
  __shared__ float wre[1024], wim[1024];
  __shared__ float fin[1024];
  const float* wr_ = (ky < 12) ? w1r : w2r;
  const float* wi_ = (ky < 12) ? w1i : w2i;
  const int kyp = (ky < 12) ? ky : ky - 12;
  for (int f = tid; f < 1024; f += 256) {
    int idx = f*144 + kyp*12 + kx;
    wre[f] = wr_[idx]; wim[f] = wi_[idx];
  }
  for (int f = tid; f < 1024; f += 256) {
    int b = f >> 6, j = f & 63;
    fin[f] = fc[((b*24 + ky)*12 + kx)*64 + j];
  }
  __syncthreads();
  for (int k = 0; k < 2; ++k) {
    int idx = tid + k*256;
    int b = idx >> 5, o = idx & 31;
    float ar = 0.f, ai = 0.f;
    #pragma unroll
    for (int i = 0; i < 32; ++i) {
      float fr = fin[b*64 + 2*i], fi2 = fin[b*64 + 2*i + 1];
      float wr = wre[i*32+o],     wi2 = wim[i*32+o];
      ar += fr*wr - fi2*wi2;
      ai += fr*wi2 + fi2*wr;
    }
    float* op = fm + ((b*24 + ky)*12 + kx)*64 + 2*o;
    op[0] = ar; op[1] = ai;
  }
}

// Inverse DFT along y: 24 modes -> 256 y. gy layout [b][y][kx][o][2]
__global__ __launch_bounds__(256) void k_inv_y(
    const float* __restrict__ fm, const float* __restrict__ cs,
    float* __restrict__ gy)
{
  const int b = blockIdx.x / 12, kx = blockIdx.x % 12;
  const int tid = threadIdx.x;
  __shared__ __align__(16) float F[1536];
  __shared__ __align__(16) float csl[512];
  for (int f = tid; f < 1536; f += 256) {
    int s = f >> 6, j = f & 63;
    F[f] = fm[((b*24 + s)*12 + kx)*64 + j];
  }
  for (int f = tid; f < 512; f += 256) csl[f] = cs[f];
  __syncthreads();
  const int y = tid;
  float tc[24], tsn[24];
  #pragma unroll
  for (int s = 0; s < 24; ++s) {
    int kyv = (s < 12) ? s : (232 + s);
    int tt = (kyv * y) & 255;
    tc[s] = csl[2*tt]; tsn[s] = csl[2*tt+1];
  }
  float* orow = gy + ((b*256 + y)*12 + kx)*64;
  for (int o2 = 0; o2 < 16; ++o2) {
    float ar0 = 0.f, ai0 = 0.f, ar1 = 0.f, ai1 = 0.f;
    #pragma unroll
    for (int s = 0; s < 24; ++s) {
      float2 f0 = *(const float2*)&F[s*64 + 4*o2];
      float2 f1 = *(const float2*)&F[s*64 + 4*o2 + 2];
      ar0 += f0.x*tc[s] - f0.y*tsn[s];
      ai0 += f0.x*tsn[s] + f0.y*tc[s];
      ar1 += f1.x*tc[s] - f1.y*tsn[s];
      ai1 += f1.x*tsn[s] + f1.y*tc[s];
    }
    float4 v;
    v.x = ar0*INV_HW; v.y = ai0*INV_HW; v.z = ar1*INV_HW; v.w = ai1*INV_HW;
    *(float4*)(orow + 4*o2) = v;
  }
}

// FUSED: inverse-x DFT + residual linear + ReLU + BN partials + next fwd-x.
// G and lw/lb are read DIRECTLY from global with wave-uniform addresses
// (compiler scalarizes to s_load / L1 broadcast — no LDS staging).
__global__ __launch_bounds__(256) void k_fuse(
    const float* __restrict__ gy, const float* __restrict__ cs,
    const float* __restrict__ lw, const float* __restrict__ lb,
    float* __restrict__ gxo, float* __restrict__ part, float* __restrict__ z)
{
  const int b = blockIdx.x >> 8, y = blockIdx.x & 255;
  const int tid = threadIdx.x;
  __shared__ __align__(16) float csl[512];
  __shared__ float S[32*257];
  for (int f = tid; f < 512; f += 256) csl[f] = cs[f];
  __syncthreads();
  const int x = tid;
  float tc[12], tsn[12];
  #pragma unroll
  for (int kx = 1; kx < 12; ++kx) {
    int tt = (kx * x) & 255;
    tc[kx]  = 2.0f*csl[2*tt];
    tsn[kx] = 2.0f*csl[2*tt+1];
  }
  const float* Gg = gy + (long)(b*256 + y)*768;   // wave-uniform base
  float yv[32];
  #pragma unroll
  for (int c = 0; c < 32; c += 2) {       // c2r: kx=0 Re only, 2x for kx>=1
    float a0 = Gg[2*c];
    float a1 = Gg[2*c + 2];
    #pragma unroll
    for (int kx = 1; kx < 12; ++kx) {
      float4 g = *(const float4*)(Gg + kx*64 + 2*c);
      a0 += g.x*tc[kx] - g.y*tsn[kx];
      a1 += g.z*tc[kx] - g.w*tsn[kx];
    }
    yv[c] = a0; yv[c+1] = a1;
  }
  float zv[32];
  const float4* lw4 = (const float4*)lw;          // uniform, L1-resident
  #pragma unroll
  for (int o = 0; o < 32; ++o) {
    float a = lb[o] + yv[o];
    #pragma unroll
    for (int c4 = 0; c4 < 8; ++c4) {
      float4 wv = lw4[o*8 + c4];
      a += yv[4*c4]*wv.x + yv[4*c4+1]*wv.y + yv[4*c4+2]*wv.z + yv[4*c4+3]*wv.w;
    }
    zv[o] = fmaxf(a, 0.0f);
  }
  if (z) {
    #pragma unroll
    for (int o = 0; o < 32; ++o)
      z[((b*32 + o)*256 + y)*256 + x] = zv[o];
  }
  #pragma unroll
  for (int o = 0; o < 32; ++o) S[o*257 + tid] = zv[o];
  __syncthreads();
  // phase B: tasks 0-5: kx-pair dots -> gx[b][y][ch][24] (one float4/lane);
  // task0's kx=0 real part doubles as the BN sum; tasks 6,7: sumsq halves.
  const int task = tid >> 5, o = tid & 31;
  if (task < 6) {
    if (gxo || task == 0) {
      const int kx0 = task*2, kx1 = kx0 + 1;
      float ar0=0.f, ai0=0.f, ar1=0.f, ai1=0.f;
      const float* Sp = &S[o*257];
      int t0 = 0, t1 = 0;
      for (int xx = 0; xx < 256; ++xx) {
        float v = Sp[xx];
        float2 w0 = *(const float2*)&csl[2*t0];
        float2 w1 = *(const float2*)&csl[2*t1];
        ar0 += v*w0.x; ai0 -= v*w0.y;
        ar1 += v*w1.x; ai1 -= v*w1.y;
        t0 = (t0 + kx0) & 255;
        t1 = (t1 + kx1) & 255;
      }
      if (task == 0) part[(long)blockIdx.x*64 + 2*o] = ar0;   // channel sum
      if (gxo) {
        float4 w4; w4.x = ar0; w4.y = ai0; w4.z = ar1; w4.w = ai1;
        *(float4*)(gxo + ((long)(b*256 + y)*32 + o)*24 + task*4) = w4;
      }
    }
  } else {
    const int xb = (task - 6) << 7;
    const float* Sp = &S[o*257];
    float sq = 0.f;
    for (int j = 0; j < 128; ++j) { float v = Sp[xb + j]; sq += v*v; }
    sq += __shfl_xor(sq, 32, 64);          // combine task6+task7 (same wave)
    if (task == 6) part[(long)blockIdx.x*64 + 2*o + 1] = sq;
  }
}

// Reduce partials -> BN scale/bias for next consumer
__global__ __launch_bounds__(256) void k_stats(
    const float* __restrict__ part, const float* __restrict__ gamma,
    const float* __restrict__ beta, float* __restrict__ bn)
{
  const int c = blockIdx.x, tid = threadIdx.x;
  float s1 = 0.f, s2 = 0.f;
  for (int j = tid; j < 4096; j += 256) {
    s1 += part[(long)j*64 + 2*c];
    s2 += part[(long)j*64 + 2*c + 1];
  }
  #pragma unroll
  for (int d = 32; d; d >>= 1) {
    s1 += __shfl_xor(s1, d, 64);
    s2 += __shfl_xor(s2, d, 64);
  }
  __shared__ float r1[4], r2[4];
  int w = tid >> 6;
  if ((tid & 63) == 0) { r1[w] = s1; r2[w] = s2; }
  __syncthreads();
  if (tid == 0) {
    float S1 = r1[0]+r1[1]+r1[2]+r1[3];
    float S2 = r2[0]+r2[1]+r2[2]+r2[3];
    const float N = 1048576.0f;
    float mean = S1 / N;
    float var  = S2 / N - mean*mean;
    float inv  = rsqrtf(var + 1e-5f);
    float sc   = gamma[c] * inv;
    bn[c]      = sc;
    bn[32 + c] = beta[c] - mean*sc;
  }
}

// Final: BN affine (layer 3) + linear_out
__global__ __launch_bounds__(256) void k_out(
    const float* __restrict__ z, const float* __restrict__ bn,
    const float* __restrict__ w_out, const float* __restrict__ b_out,
    float* __restrict__ out)
{
  __shared__ float a[32];
  __shared__ float c0s;
  const int tid = threadIdx.x;
  if (tid < 32) a[tid] = bn[tid] * w_out[tid];
  if (tid == 0) {
    float t = b_out[0];
    for (int c = 0; c < 32; ++c) t += bn[32 + c] * w_out[c];
    c0s = t;
  }
  __syncthreads();
  int gid = blockIdx.x*256 + tid;             // [0, 262144)
  int b = gid >> 14, pos = (gid & 16383) << 2;
  const float* zb = z + (long)b*2097152 + pos;
  float c0 = c0s;
  float r0 = c0, r1 = c0, r2 = c0, r3 = c0;
  #pragma unroll 8
  for (int c = 0; c < 32; ++c) {
    float4 v = *(const float4*)(zb + c*65536);
    float ac = a[c];
    r0 += v.x*ac; r1 += v.y*ac; r2 += v.z*ac; r3 += v.w*ac;
  }
  float4 res; res.x = r0; res.y = r1; res.z = r2; res.w = r3;
  *(float4*)(out + (long)b*65536 + pos) = res;
}

extern "C" void kernel_launch(void* const* d_in, const int* in_sizes, int n_in,
                              void* d_out, int out_size, void* d_ws, size_t ws_size,
                              hipStream_t stream) {
  const float* x      = (const float*)d_in[0];
  const float* coords = (const float*)d_in[1];
  const float* w_in   = (const float*)d_in[2];
  const float* b_in   = (const float*)d_in[3];
  const float* w1r    = (const float*)d_in[4];
  const float* w1i    = (const float*)d_in[5];
  const float* w2r    = (const float*)d_in[6];
  const float* w2i    = (const float*)d_in[7];
  const float* lw     = (const float*)d_in[8];
  const float* lb     = (const float*)d_in[9];
  const float* gamma  = (const float*)d_in[10];
  const float* beta   = (const float*)d_in[11];
  const float* w_out  = (const float*)d_in[12];
  const float* b_out  = (const float*)d_in[13];
  float* out = (float*)d_out;
  float* ws  = (float*)d_ws;

  float* cs   = ws;
  float* z    = cs + 512;            // gx aliases z[0:3145728]
  float* gx   = z;
  float* gy   = z + 33554432;
  float* fc   = gy + 3145728;        // part aliases fc
  float* fm   = fc + 294912;
  float* bn   = fm + 294912;
  float* part = fc;

  k_init<<<1, 256, 0, stream>>>(cs);
  k_embed_fwd<<<4096, 256, 0, stream>>>(x, coords, w_in, b_in, cs, gx);

  for (int l = 0; l < 4; ++l) {
    k_fwd_y<<<768, 256, 0, stream>>>(gx, cs, (l == 0) ? nullptr : bn, fc);
    k_mix<<<288, 256, 0, stream>>>(fc, fm, w1r + l*147456, w1i + l*147456,
                                   w2r + l*147456, w2i + l*147456);
    k_inv_y<<<192, 256, 0, stream>>>(fm, cs, gy);
    k_fuse<<<4096, 256, 0, stream>>>(gy, cs, lw + l*1024, lb + l*32,
                                     (l < 3) ? gx : nullptr, part,
                                     (l == 3) ? z : nullptr);
    k_stats<<<32, 256, 0, stream>>>(part, gamma + l*32, beta + l*32, bn);
  }

  k_out<<<1024, 256, 0, stream>>>(z, bn, w_out, b_out, out);
}

// Round 10
// 752.512 us; speedup vs baseline: 1.1730x; 1.1730x over previous
//
#include <hip/hip_runtime.h>

constexpr double PI2 = 6.283185307179586476925286766559;
constexpr float INV_HW = 1.0f / 65536.0f;

// B=16, D=32, H=W=256, M=12, L=4
// ws (floats), total 37,290,560 (142.25 MiB — proven safe):
//   cs[512] | z[33554432] | gy[3145728] | fc[294912] | fm[294912] | bn[64]
//   gx ALIASES z[0:3145728]; wf (fused mix weights, 2,359,296) ALIASES
//   z[3145728:5505024] (z only written by layer-3 k_fuse, after last wf read);
//   part (262144) ALIASES fc.
// gx layout: [b][y][ch32][mode24]; wf layout: [l][ky*12+kx][re1024|im1024].

__global__ __launch_bounds__(256) void k_init(float* __restrict__ cs) {
  int t = threadIdx.x;
  double a = PI2 * (double)t / 256.0;
  cs[2*t]   = (float)cos(a);
  cs[2*t+1] = (float)sin(a);
}

// Fold residual pointwise linear (I + lw) into the spectral mix weights:
// W'[i][o] = w[i][o] + sum_c w[i][c] * lw[o][c]   (complex w, real lw)
// block = l*288 + ky*12 + kx
__global__ __launch_bounds__(256) void k_prep(
    const float* __restrict__ w1r, const float* __restrict__ w1i,
    const float* __restrict__ w2r, const float* __restrict__ w2i,
    const float* __restrict__ lw, float* __restrict__ wf)
{
  const int bid = blockIdx.x;
  const int l = bid / 288, m = bid % 288;
  const int ky = m / 12, kx = m % 12;
  const int kyp = (ky < 12) ? ky : ky - 12;
  const float* wr_ = ((ky < 12) ? w1r : w2r) + l*147456;
  const float* wi_ = ((ky < 12) ? w1i : w2i) + l*147456;
  __shared__ float wre[1024], wim[1024], lwl[1024];
  const int tid = threadIdx.x;
  for (int f = tid; f < 1024; f += 256) {
    int idx = f*144 + kyp*12 + kx;
    wre[f] = wr_[idx]; wim[f] = wi_[idx];
    lwl[f] = lw[l*1024 + f];
  }
  __syncthreads();
  float* o_ = wf + (long)bid*2048;
  for (int f = tid; f < 1024; f += 256) {
    int i = f >> 5, o = f & 31;
    float ar = wre[f], ai = wim[f];
    #pragma unroll
    for (int c = 0; c < 32; ++c) {
      float lv = lwl[o*32 + c];
      ar += wre[i*32 + c] * lv;
      ai += wim[i*32 + c] * lv;
    }
    o_[f] = ar; o_[1024 + f] = ai;
  }
}

// Layer-0: h0 in registers -> x-DFT to 12 modes -> gx[b][y][ch][24]
__global__ __launch_bounds__(256) void k_embed_fwd(
    const float* __restrict__ xin, const float* __restrict__ coords,
    const float* __restrict__ w_in, const float* __restrict__ b_in,
    const float* __restrict__ cs, float* __restrict__ gxo)
{
  __shared__ float wl[96], bl[32];
  __shared__ __align__(16) float csl[512];
  __shared__ float S[32*257];
  const int tid = threadIdx.x;
  if (tid < 96) wl[tid] = w_in[tid];
  if (tid >= 96 && tid < 128) bl[tid-96] = b_in[tid-96];
  for (int f = tid; f < 512; f += 256) csl[f] = cs[f];
  const int b = blockIdx.x >> 8, y = blockIdx.x & 255;
  const float xv = xin[(b*256 + y)*256 + tid];
  const float c0 = coords[y*256 + tid];
  const float c1 = coords[65536 + y*256 + tid];
  __syncthreads();
  #pragma unroll 8
  for (int d = 0; d < 32; ++d)
    S[d*257 + tid] = wl[3*d]*xv + wl[3*d+1]*c0 + wl[3*d+2]*c1 + bl[d];
  __syncthreads();
  const int task = tid >> 5, o = tid & 31;
  if (task < 6) {
    const int kx0 = task*2, kx1 = kx0 + 1;
    float ar0=0.f, ai0=0.f, ar1=0.f, ai1=0.f;
    const float* Sp = &S[o*257];
    int t0 = 0, t1 = 0;
    for (int xx = 0; xx < 256; ++xx) {
      float v = Sp[xx];
      float2 w0 = *(const float2*)&csl[2*t0];
      float2 w1 = *(const float2*)&csl[2*t1];
      ar0 += v*w0.x; ai0 -= v*w0.y;
      ar1 += v*w1.x; ai1 -= v*w1.y;
      t0 = (t0 + kx0) & 255;
      t1 = (t1 + kx1) & 255;
    }
    float4 w4; w4.x = ar0; w4.y = ai0; w4.z = ar1; w4.w = ai1;
    *(float4*)(gxo + ((long)(b*256 + y)*32 + o)*24 + task*4) = w4;
  }
}

// Forward DFT along y with BN-affine fold on staging.
// Reads gx[b][y][ch][mode]; fc layout [b][ky24][kx12][C32][2]
__global__ __launch_bounds__(256) void k_fwd_y(
    const float* __restrict__ gx, const float* __restrict__ cs,
    const float* __restrict__ bnp, float* __restrict__ fc)
{
  __shared__ __align__(16) float R[8*528];
  __shared__ __align__(16) float csl[512];
  const int tid = threadIdx.x;
  for (int f = tid; f < 512; f += 256) csl[f] = cs[f];
  const int g = tid >> 5, s = tid & 31;
  const int task = blockIdx.x*8 + g;        // [0, 6144)
  const int bc = task / 12, kx = task % 12;
  const int bb = bc >> 5, ch = bc & 31;
  {
    const float* rr = gx + ((long)(bb*256)*32 + ch)*24 + 2*kx;  // + y*768
    float sc = 1.0f, badd = 0.0f;
    if (bnp) {
      sc = bnp[ch];
      badd = (kx == 0) ? 256.0f*bnp[32 + ch] : 0.0f;
    }
    for (int i = 0; i < 8; ++i) {          // 32 lanes x 8 = 256 y
      int y = s + 32*i;
      float2 v = *(const float2*)(rr + (long)y*768);
      R[g*528 + 2*y]     = sc*v.x + badd;
      R[g*528 + 2*y + 1] = sc*v.y;
    }
  }
  __syncthreads();
  if (s < 24) {
    const int kyv = (s < 12) ? s : (232 + s);
    float ar = 0.f, ai = 0.f;
    int tt = 0;
    const float* Rg = &R[g*528];
    for (int y = 0; y < 256; ++y) {
      float2 v = *(const float2*)&Rg[2*y];
      float2 w = *(const float2*)&csl[2*tt];
      ar += v.x*w.x + v.y*w.y;      // v * conj(e^{i theta})
      ai += v.y*w.x - v.x*w.y;
      tt = (tt + kyv) & 255;
    }
    float* o = fc + ((bb*24 + s)*12 + kx)*64 + 2*ch;
    o[0] = ar; o[1] = ai;
  }
}

// Per-mode complex channel mix with PRE-FOLDED weights (contiguous layout):
// out[b,o] = sum_i fin[b,i] * W'[i,o]
__global__ __launch_bounds__(256) void k_mix(
    const float* __restrict__ fc, float* __restrict__ fm,
    const float* __restrict__ wfl)
{
  const int ky = blockIdx.x / 12, kx = blockIdx.x % 12;
  const int tid = threadIdx.x;
  __shared__ float wre[1024], wim[1024];
  __shared__ float fin[1024];
  const float* wb = wfl + (long)blockIdx.x*2048;
  for (int f = tid; f < 1024; f += 256) {
    wre[f] = wb[f];
    wim[f] = wb[1024 + f];
  }
  for (int f = tid; f < 1024; f += 256) {
    int b = f >> 6, j = f & 63;
    fin[f] = fc[((b*24 + ky)*12 + kx)*64 + j];
  }
  __syncthreads();
  for (int k = 0; k < 2; ++k) {
    int idx = tid + k*256;
    int b = idx >> 5, o = idx & 31;
    float ar = 0.f, ai = 0.f;
    #pragma unroll
    for (int i = 0; i < 32; ++i) {
      float fr = fin[b*64 + 2*i], fi2 = fin[b*64 + 2*i + 1];
      float wr = wre[i*32+o],     wi2 = wim[i*32+o];
      ar += fr*wr - fi2*wi2;
      ai += fr*wi2 + fi2*wr;
    }
    float* op = fm + ((b*24 + ky)*12 + kx)*64 + 2*o;
    op[0] = ar; op[1] = ai;
  }
}

// Inverse DFT along y: 24 modes -> 256 y. gy layout [b][y][kx][o][2]
__global__ __launch_bounds__(256) void k_inv_y(
    const float* __restrict__ fm, const float* __restrict__ cs,
    float* __restrict__ gy)
{
  const int b = blockIdx.x / 12, kx = blockIdx.x % 12;
  const int tid = threadIdx.x;
  __shared__ __align__(16) float F[1536];
  __shared__ __align__(16) float csl[512];
  for (int f = tid; f < 1536; f += 256) {
    int s = f >> 6, j = f & 63;
    F[f] = fm[((b*24 + s)*12 + kx)*64 + j];
  }
  for (int f = tid; f < 512; f += 256) csl[f] = cs[f];
  __syncthreads();
  const int y = tid;
  float tc[24], tsn[24];
  #pragma unroll
  for (int s = 0; s < 24; ++s) {
    int kyv = (s < 12) ? s : (232 + s);
    int tt = (kyv * y) & 255;
    tc[s] = csl[2*tt]; tsn[s] = csl[2*tt+1];
  }
  float* orow = gy + ((b*256 + y)*12 + kx)*64;
  for (int o2 = 0; o2 < 16; ++o2) {
    float ar0 = 0.f, ai0 = 0.f, ar1 = 0.f, ai1 = 0.f;
    #pragma unroll
    for (int s = 0; s < 24; ++s) {
      float2 f0 = *(const float2*)&F[s*64 + 4*o2];
      float2 f1 = *(const float2*)&F[s*64 + 4*o2 + 2];
      ar0 += f0.x*tc[s] - f0.y*tsn[s];
      ai0 += f0.x*tsn[s] + f0.y*tc[s];
      ar1 += f1.x*tc[s] - f1.y*tsn[s];
      ai1 += f1.x*tsn[s] + f1.y*tc[s];
    }
    float4 v;
    v.x = ar0*INV_HW; v.y = ai0*INV_HW; v.z = ar1*INV_HW; v.w = ai1*INV_HW;
    *(float4*)(orow + 4*o2) = v;
  }
}

// FUSED: inverse-x DFT (+lb, relu; linear pre-folded into mix weights)
// + BN partials + next layer's forward-x DFT.
__global__ __launch_bounds__(256) void k_fuse(
    const float* __restrict__ gy, const float* __restrict__ cs,
    const float* __restrict__ lb,
    float* __restrict__ gxo, float* __restrict__ part, float* __restrict__ z)
{
  const int b = blockIdx.x >> 8, y = blockIdx.x & 255;
  const int tid = threadIdx.x;
  __shared__ __align__(16) float csl[512];
  __shared__ float S[32*257];
  for (int f = tid; f < 512; f += 256) csl[f] = cs[f];
  __syncthreads();
  const int x = tid;
  float tc[12], tsn[12];
  #pragma unroll
  for (int kx = 1; kx < 12; ++kx) {
    int tt = (kx * x) & 255;
    tc[kx]  = 2.0f*csl[2*tt];
    tsn[kx] = 2.0f*csl[2*tt+1];
  }
  const float* Gg = gy + (long)(b*256 + y)*768;   // wave-uniform base
  float zv[32];
  #pragma unroll
  for (int c = 0; c < 32; c += 2) {       // c2r: kx=0 Re only, 2x for kx>=1
    float a0 = Gg[2*c];
    float a1 = Gg[2*c + 2];
    #pragma unroll
    for (int kx = 1; kx < 12; ++kx) {
      float4 g = *(const float4*)(Gg + kx*64 + 2*c);
      a0 += g.x*tc[kx] - g.y*tsn[kx];
      a1 += g.z*tc[kx] - g.w*tsn[kx];
    }
    zv[c]   = fmaxf(a0 + lb[c], 0.0f);
    zv[c+1] = fmaxf(a1 + lb[c+1], 0.0f);
  }
  if (z) {
    #pragma unroll
    for (int o = 0; o < 32; ++o)
      z[((b*32 + o)*256 + y)*256 + x] = zv[o];
  }
  #pragma unroll
  for (int o = 0; o < 32; ++o) S[o*257 + tid] = zv[o];
  __syncthreads();
  // phase B: tasks 0-5: kx-pair dots -> gx[b][y][ch][24] (one float4/lane);
  // task0's kx=0 real part doubles as the BN sum; tasks 6,7: sumsq halves.
  const int task = tid >> 5, o = tid & 31;
  if (task < 6) {
    if (gxo || task == 0) {
      const int kx0 = task*2, kx1 = kx0 + 1;
      float ar0=0.f, ai0=0.f, ar1=0.f, ai1=0.f;
      const float* Sp = &S[o*257];
      int t0 = 0, t1 = 0;
      for (int xx = 0; xx < 256; ++xx) {
        float v = Sp[xx];
        float2 w0 = *(const float2*)&csl[2*t0];
        float2 w1 = *(const float2*)&csl[2*t1];
        ar0 += v*w0.x; ai0 -= v*w0.y;
        ar1 += v*w1.x; ai1 -= v*w1.y;
        t0 = (t0 + kx0) & 255;
        t1 = (t1 + kx1) & 255;
      }
      if (task == 0) part[(long)blockIdx.x*64 + 2*o] = ar0;   // channel sum
      if (gxo) {
        float4 w4; w4.x = ar0; w4.y = ai0; w4.z = ar1; w4.w = ai1;
        *(float4*)(gxo + ((long)(b*256 + y)*32 + o)*24 + task*4) = w4;
      }
    }
  } else {
    const int xb = (task - 6) << 7;
    const float* Sp = &S[o*257];
    float sq = 0.f;
    for (int j = 0; j < 128; ++j) { float v = Sp[xb + j]; sq += v*v; }
    sq += __shfl_xor(sq, 32, 64);          // combine task6+task7 (same wave)
    if (task == 6) part[(long)blockIdx.x*64 + 2*o + 1] = sq;
  }
}

// Reduce partials -> BN scale/bias for next consumer
__global__ __launch_bounds__(256) void k_stats(
    const float* __restrict__ part, const float* __restrict__ gamma,
    const float* __restrict__ beta, float* __restrict__ bn)
{
  const int c = blockIdx.x, tid = threadIdx.x;
  float s1 = 0.f, s2 = 0.f;
  for (int j = tid; j < 4096; j += 256) {
    s1 += part[(long)j*64 + 2*c];
    s2 += part[(long)j*64 + 2*c + 1];
  }
  #pragma unroll
  for (int d = 32; d; d >>= 1) {
    s1 += __shfl_xor(s1, d, 64);
    s2 += __shfl_xor(s2, d, 64);
  }
  __shared__ float r1[4], r2[4];
  int w = tid >> 6;
  if ((tid & 63) == 0) { r1[w] = s1; r2[w] = s2; }
  __syncthreads();
  if (tid == 0) {
    float S1 = r1[0]+r1[1]+r1[2]+r1[3];
    float S2 = r2[0]+r2[1]+r2[2]+r2[3];
    const float N = 1048576.0f;
    float mean = S1 / N;
    float var  = S2 / N - mean*mean;
    float inv  = rsqrtf(var + 1e-5f);
    float sc   = gamma[c] * inv;
    bn[c]      = sc;
    bn[32 + c] = beta[c] - mean*sc;
  }
}

// Final: BN affine (layer 3) + linear_out
__global__ __launch_bounds__(256) void k_out(
    const float* __restrict__ z, const float* __restrict__ bn,
    const float* __restrict__ w_out, const float* __restrict__ b_out,
    float* __restrict__ out)
{
  __shared__ float a[32];
  __shared__ float c0s;
  const int tid = threadIdx.x;
  if (tid < 32) a[tid] = bn[tid] * w_out[tid];
  if (tid == 0) {
    float t = b_out[0];
    for (int c = 0; c < 32; ++c) t += bn[32 + c] * w_out[c];
    c0s = t;
  }
  __syncthreads();
  int gid = blockIdx.x*256 + tid;             // [0, 262144)
  int b = gid >> 14, pos = (gid & 16383) << 2;
  const float* zb = z + (long)b*2097152 + pos;
  float c0 = c0s;
  float r0 = c0, r1 = c0, r2 = c0, r3 = c0;
  #pragma unroll 8
  for (int c = 0; c < 32; ++c) {
    float4 v = *(const float4*)(zb + c*65536);
    float ac = a[c];
    r0 += v.x*ac; r1 += v.y*ac; r2 += v.z*ac; r3 += v.w*ac;
  }
  float4 res; res.x = r0; res.y = r1; res.z = r2; res.w = r3;
  *(float4*)(out + (long)b*65536 + pos) = res;
}

extern "C" void kernel_launch(void* const* d_in, const int* in_sizes, int n_in,
                              void* d_out, int out_size, void* d_ws, size_t ws_size,
                              hipStream_t stream) {
  const float* x      = (const float*)d_in[0];
  const float* coords = (const float*)d_in[1];
  const float* w_in   = (const float*)d_in[2];
  const float* b_in   = (const float*)d_in[3];
  const float* w1r    = (const float*)d_in[4];
  const float* w1i    = (const float*)d_in[5];
  const float* w2r    = (const float*)d_in[6];
  const float* w2i    = (const float*)d_in[7];
  const float* lw     = (const float*)d_in[8];
  const float* lb     = (const float*)d_in[9];
  const float* gamma  = (const float*)d_in[10];
  const float* beta   = (const float*)d_in[11];
  const float* w_out  = (const float*)d_in[12];
  const float* b_out  = (const float*)d_in[13];
  float* out = (float*)d_out;
  float* ws  = (float*)d_ws;

  float* cs   = ws;
  float* z    = cs + 512;            // gx aliases z[0:3145728]
  float* gx   = z;
  float* wf   = z + 3145728;         // fused weights alias z[3.1M:5.5M]
  float* gy   = z + 33554432;
  float* fc   = gy + 3145728;        // part aliases fc
  float* fm   = fc + 294912;
  float* bn   = fm + 294912;
  float* part = fc;

  k_init<<<1, 256, 0, stream>>>(cs);
  k_prep<<<1152, 256, 0, stream>>>(w1r, w1i, w2r, w2i, lw, wf);
  k_embed_fwd<<<4096, 256, 0, stream>>>(x, coords, w_in, b_in, cs, gx);

  for (int l = 0; l < 4; ++l) {
    k_fwd_y<<<768, 256, 0, stream>>>(gx, cs, (l == 0) ? nullptr : bn, fc);
    k_mix<<<288, 256, 0, stream>>>(fc, fm, wf + (long)l*589824);
    k_inv_y<<<192, 256, 0, stream>>>(fm, cs, gy);
    k_fuse<<<4096, 256, 0, stream>>>(gy, cs, lb + l*32,
                                     (l < 3) ? gx : nullptr, part,
                                     (l == 3) ? z : nullptr);
    k_stats<<<32, 256, 0, stream>>>(part, gamma + l*32, beta + l*32, bn);
  }

  k_out<<<1024, 256, 0, stream>>>(z, bn, w_out, b_out, out);
}

// Round 11
// 680.532 us; speedup vs baseline: 1.2971x; 1.1058x over previous
//
#include <hip/hip_runtime.h>

constexpr double PI2 = 6.283185307179586476925286766559;
constexpr float INV_HW = 1.0f / 65536.0f;

// B=16, D=32, H=W=256, M=12, L=4
// ws (floats), total 37,290,560 (142.25 MiB — proven safe):
//   cs[512] | z[33554432] | gy[3145728] | fc[294912] | fm[294912] | bn[64]
//   gx ALIASES z[0:3145728]; wf ALIASES z[3145728:5505024]; part ALIASES fc.
// gx layout: [b][y][ch32][mode24]; wf layout: [l][ky*12+kx][re1024|im1024].

__global__ __launch_bounds__(256) void k_init(float* __restrict__ cs) {
  int t = threadIdx.x;
  double a = PI2 * (double)t / 256.0;
  cs[2*t]   = (float)cos(a);
  cs[2*t+1] = (float)sin(a);
}

// Fold residual pointwise linear (I + lw) into the spectral mix weights:
// W'[i][o] = w[i][o] + sum_c w[i][c] * lw[o][c]
__global__ __launch_bounds__(256) void k_prep(
    const float* __restrict__ w1r, const float* __restrict__ w1i,
    const float* __restrict__ w2r, const float* __restrict__ w2i,
    const float* __restrict__ lw, float* __restrict__ wf)
{
  const int bid = blockIdx.x;
  const int l = bid / 288, m = bid % 288;
  const int ky = m / 12, kx = m % 12;
  const int kyp = (ky < 12) ? ky : ky - 12;
  const float* wr_ = ((ky < 12) ? w1r : w2r) + l*147456;
  const float* wi_ = ((ky < 12) ? w1i : w2i) + l*147456;
  __shared__ float wre[1024], wim[1024], lwl[1024];
  const int tid = threadIdx.x;
  for (int f = tid; f < 1024; f += 256) {
    int idx = f*144 + kyp*12 + kx;
    wre[f] = wr_[idx]; wim[f] = wi_[idx];
    lwl[f] = lw[l*1024 + f];
  }
  __syncthreads();
  float* o_ = wf + (long)bid*2048;
  for (int f = tid; f < 1024; f += 256) {
    int i = f >> 5, o = f & 31;
    float ar = wre[f], ai = wim[f];
    #pragma unroll
    for (int c = 0; c < 32; ++c) {
      float lv = lwl[o*32 + c];
      ar += wre[i*32 + c] * lv;
      ai += wim[i*32 + c] * lv;
    }
    o_[f] = ar; o_[1024 + f] = ai;
  }
}

// Layer-0: h0 in registers -> x-DFT (even/odd real-input form) -> gx
__global__ __launch_bounds__(256) void k_embed_fwd(
    const float* __restrict__ xin, const float* __restrict__ coords,
    const float* __restrict__ w_in, const float* __restrict__ b_in,
    const float* __restrict__ cs, float* __restrict__ gxo)
{
  __shared__ float wl[96], bl[32];
  __shared__ __align__(16) float csl[512];
  __shared__ float S[32*257];
  const int tid = threadIdx.x;
  if (tid < 96) wl[tid] = w_in[tid];
  if (tid >= 96 && tid < 128) bl[tid-96] = b_in[tid-96];
  for (int f = tid; f < 512; f += 256) csl[f] = cs[f];
  const int b = blockIdx.x >> 8, y = blockIdx.x & 255;
  const float xv = xin[(b*256 + y)*256 + tid];
  const float c0 = coords[y*256 + tid];
  const float c1 = coords[65536 + y*256 + tid];
  __syncthreads();
  #pragma unroll 8
  for (int d = 0; d < 32; ++d)
    S[d*257 + tid] = wl[3*d]*xv + wl[3*d+1]*c0 + wl[3*d+2]*c1 + bl[d];
  __syncthreads();
  const int task = tid >> 5, o = tid & 31;
  if (task < 6) {
    const int kx0 = task*2, kx1 = kx0 + 1;   // kx0 even, kx1 odd
    const float* Sp = &S[o*257];
    const float s0v = Sp[0], s128 = Sp[128];
    float ar0 = s0v + s128, ai0 = 0.f;
    float ar1 = s0v - s128, ai1 = 0.f;
    int t0 = kx0, t1 = kx1;                  // angle index at x=1
    for (int xx = 1; xx < 128; ++xx) {
      float a = Sp[xx], bv = Sp[256 - xx];
      float e = a + bv, od = a - bv;
      float2 w0 = *(const float2*)&csl[2*t0];
      float2 w1 = *(const float2*)&csl[2*t1];
      ar0 += e*w0.x;  ai0 -= od*w0.y;
      ar1 += e*w1.x;  ai1 -= od*w1.y;
      t0 = (t0 + kx0) & 255;
      t1 = (t1 + kx1) & 255;
    }
    float4 w4; w4.x = ar0; w4.y = ai0; w4.z = ar1; w4.w = ai1;
    *(float4*)(gxo + ((long)(b*256 + y)*32 + o)*24 + task*4) = w4;
  }
}

// Forward DFT along y with BN-affine fold on staging.
// Reads gx[b][y][ch][mode]; fc layout [b][ky24][kx12][C32][2]
__global__ __launch_bounds__(256) void k_fwd_y(
    const float* __restrict__ gx, const float* __restrict__ cs,
    const float* __restrict__ bnp, float* __restrict__ fc)
{
  __shared__ __align__(16) float R[8*528];
  __shared__ __align__(16) float csl[512];
  const int tid = threadIdx.x;
  for (int f = tid; f < 512; f += 256) csl[f] = cs[f];
  const int g = tid >> 5, s = tid & 31;
  const int task = blockIdx.x*8 + g;        // [0, 6144)
  const int bc = task / 12, kx = task % 12;
  const int bb = bc >> 5, ch = bc & 31;
  {
    const float* rr = gx + ((long)(bb*256)*32 + ch)*24 + 2*kx;  // + y*768
    float sc = 1.0f, badd = 0.0f;
    if (bnp) {
      sc = bnp[ch];
      badd = (kx == 0) ? 256.0f*bnp[32 + ch] : 0.0f;
    }
    for (int i = 0; i < 8; ++i) {          // 32 lanes x 8 = 256 y
      int y = s + 32*i;
      float2 v = *(const float2*)(rr + (long)y*768);
      R[g*528 + 2*y]     = sc*v.x + badd;
      R[g*528 + 2*y + 1] = sc*v.y;
    }
  }
  __syncthreads();
  if (s < 24) {
    const int kyv = (s < 12) ? s : (232 + s);
    float ar = 0.f, ai = 0.f;
    int tt = 0;
    const float* Rg = &R[g*528];
    for (int y = 0; y < 256; ++y) {
      float2 v = *(const float2*)&Rg[2*y];
      float2 w = *(const float2*)&csl[2*tt];
      ar += v.x*w.x + v.y*w.y;      // v * conj(e^{i theta})
      ai += v.y*w.x - v.x*w.y;
      tt = (tt + kyv) & 255;
    }
    float* o = fc + ((bb*24 + s)*12 + kx)*64 + 2*ch;
    o[0] = ar; o[1] = ai;
  }
}

// Per-mode complex channel mix with pre-folded weights.
__global__ __launch_bounds__(256) void k_mix(
    const float* __restrict__ fc, float* __restrict__ fm,
    const float* __restrict__ wfl)
{
  const int ky = blockIdx.x / 12, kx = blockIdx.x % 12;
  const int tid = threadIdx.x;
  __shared__ float wre[1024], wim[1024];
  __shared__ float fin[1024];
  const float* wb = wfl + (long)blockIdx.x*2048;
  for (int f = tid; f < 1024; f += 256) {
    wre[f] = wb[f];
    wim[f] = wb[1024 + f];
  }
  for (int f = tid; f < 1024; f += 256) {
    int b = f >> 6, j = f & 63;
    fin[f] = fc[((b*24 + ky)*12 + kx)*64 + j];
  }
  __syncthreads();
  for (int k = 0; k < 2; ++k) {
    int idx = tid + k*256;
    int b = idx >> 5, o = idx & 31;
    float ar = 0.f, ai = 0.f;
    #pragma unroll
    for (int i = 0; i < 32; ++i) {
      float fr = fin[b*64 + 2*i], fi2 = fin[b*64 + 2*i + 1];
      float wr = wre[i*32+o],     wi2 = wim[i*32+o];
      ar += fr*wr - fi2*wi2;
      ai += fr*wi2 + fi2*wr;
    }
    float* op = fm + ((b*24 + ky)*12 + kx)*64 + 2*o;
    op[0] = ar; op[1] = ai;
  }
}

// Inverse DFT along y: 24 modes -> 256 y. gy layout [b][y][kx][o][2]
__global__ __launch_bounds__(256) void k_inv_y(
    const float* __restrict__ fm, const float* __restrict__ cs,
    float* __restrict__ gy)
{
  const int b = blockIdx.x / 12, kx = blockIdx.x % 12;
  const int tid = threadIdx.x;
  __shared__ __align__(16) float F[1536];
  __shared__ __align__(16) float csl[512];
  for (int f = tid; f < 1536; f += 256) {
    int s = f >> 6, j = f & 63;
    F[f] = fm[((b*24 + s)*12 + kx)*64 + j];
  }
  for (int f = tid; f < 512; f += 256) csl[f] = cs[f];
  __syncthreads();
  const int y = tid;
  float tc[24], tsn[24];
  #pragma unroll
  for (int s = 0; s < 24; ++s) {
    int kyv = (s < 12) ? s : (232 + s);
    int tt = (kyv * y) & 255;
    tc[s] = csl[2*tt]; tsn[s] = csl[2*tt+1];
  }
  float* orow = gy + ((b*256 + y)*12 + kx)*64;
  for (int o2 = 0; o2 < 16; ++o2) {
    float ar0 = 0.f, ai0 = 0.f, ar1 = 0.f, ai1 = 0.f;
    #pragma unroll
    for (int s = 0; s < 24; ++s) {
      float2 f0 = *(const float2*)&F[s*64 + 4*o2];
      float2 f1 = *(const float2*)&F[s*64 + 4*o2 + 2];
      ar0 += f0.x*tc[s] - f0.y*tsn[s];
      ai0 += f0.x*tsn[s] + f0.y*tc[s];
      ar1 += f1.x*tc[s] - f1.y*tsn[s];
      ai1 += f1.x*tsn[s] + f1.y*tc[s];
    }
    float4 v;
    v.x = ar0*INV_HW; v.y = ai0*INV_HW; v.z = ar1*INV_HW; v.w = ai1*INV_HW;
    *(float4*)(orow + 4*o2) = v;
  }
}

// FUSED: inverse-x DFT (+lb, relu) + BN partials + next fwd-x (even/odd).
__global__ __launch_bounds__(256) void k_fuse(
    const float* __restrict__ gy, const float* __restrict__ cs,
    const float* __restrict__ lb,
    float* __restrict__ gxo, float* __restrict__ part, float* __restrict__ z)
{
  const int b = blockIdx.x >> 8, y = blockIdx.x & 255;
  const int tid = threadIdx.x;
  __shared__ __align__(16) float csl[512];
  __shared__ float S[32*257];
  for (int f = tid; f < 512; f += 256) csl[f] = cs[f];
  __syncthreads();
  const int x = tid;
  float tc[12], tsn[12];
  #pragma unroll
  for (int kx = 1; kx < 12; ++kx) {
    int tt = (kx * x) & 255;
    tc[kx]  = 2.0f*csl[2*tt];
    tsn[kx] = 2.0f*csl[2*tt+1];
  }
  const float* Gg = gy + (long)(b*256 + y)*768;   // wave-uniform base
  float zv[32];
  #pragma unroll
  for (int c = 0; c < 32; c += 2) {       // c2r: kx=0 Re only, 2x for kx>=1
    float a0 = Gg[2*c];
    float a1 = Gg[2*c + 2];
    #pragma unroll
    for (int kx = 1; kx < 12; ++kx) {
      float4 g = *(const float4*)(Gg + kx*64 + 2*c);
      a0 += g.x*tc[kx] - g.y*tsn[kx];
      a1 += g.z*tc[kx] - g.w*tsn[kx];
    }
    zv[c]   = fmaxf(a0 + lb[c], 0.0f);
    zv[c+1] = fmaxf(a1 + lb[c+1], 0.0f);
  }
  if (z) {
    #pragma unroll
    for (int o = 0; o < 32; ++o)
      z[((b*32 + o)*256 + y)*256 + x] = zv[o];
  }
  #pragma unroll
  for (int o = 0; o < 32; ++o) S[o*257 + tid] = zv[o];
  __syncthreads();
  // phase B: real-input DFT via even/odd halves. tasks 0-5: mode pairs;
  // task0's kx=0 real part doubles as the BN sum; tasks 6,7: sumsq halves.
  const int task = tid >> 5, o = tid & 31;
  if (task < 6) {
    if (gxo || task == 0) {
      const int kx0 = task*2, kx1 = kx0 + 1;   // kx0 even, kx1 odd
      const float* Sp = &S[o*257];
      const float s0v = Sp[0], s128 = Sp[128];
      float ar0 = s0v + s128, ai0 = 0.f;       // cos(pi*kx0) = +1
      float ar1 = s0v - s128, ai1 = 0.f;       // cos(pi*kx1) = -1
      int t0 = kx0, t1 = kx1;                  // angle index at x=1
      for (int xx = 1; xx < 128; ++xx) {
        float a = Sp[xx], bv = Sp[256 - xx];
        float e = a + bv, od = a - bv;
        float2 w0 = *(const float2*)&csl[2*t0];
        float2 w1 = *(const float2*)&csl[2*t1];
        ar0 += e*w0.x;  ai0 -= od*w0.y;
        ar1 += e*w1.x;  ai1 -= od*w1.y;
        t0 = (t0 + kx0) & 255;
        t1 = (t1 + kx1) & 255;
      }
      if (task == 0) part[(long)blockIdx.x*64 + 2*o] = ar0;   // channel sum
      if (gxo) {
        float4 w4; w4.x = ar0; w4.y = ai0; w4.z = ar1; w4.w = ai1;
        *(float4*)(gxo + ((long)(b*256 + y)*32 + o)*24 + task*4) = w4;
      }
    }
  } else {
    const int xb = (task - 6) << 7;
    const float* Sp = &S[o*257];
    float sq = 0.f;
    for (int j = 0; j < 128; ++j) { float v = Sp[xb + j]; sq += v*v; }
    sq += __shfl_xor(sq, 32, 64);          // combine task6+task7 (same wave)
    if (task == 6) part[(long)blockIdx.x*64 + 2*o + 1] = sq;
  }
}

// Reduce partials -> BN scale/bias for next consumer
__global__ __launch_bounds__(256) void k_stats(
    const float* __restrict__ part, const float* __restrict__ gamma,
    const float* __restrict__ beta, float* __restrict__ bn)
{
  const int c = blockIdx.x, tid = threadIdx.x;
  float s1 = 0.f, s2 = 0.f;
  for (int j = tid; j < 4096; j += 256) {
    s1 += part[(long)j*64 + 2*c];
    s2 += part[(long)j*64 + 2*c + 1];
  }
  #pragma unroll
  for (int d = 32; d; d >>= 1) {
    s1 += __shfl_xor(s1, d, 64);
    s2 += __shfl_xor(s2, d, 64);
  }
  __shared__ float r1[4], r2[4];
  int w = tid >> 6;
  if ((tid & 63) == 0) { r1[w] = s1; r2[w] = s2; }
  __syncthreads();
  if (tid == 0) {
    float S1 = r1[0]+r1[1]+r1[2]+r1[3];
    float S2 = r2[0]+r2[1]+r2[2]+r2[3];
    const float N = 1048576.0f;
    float mean = S1 / N;
    float var  = S2 / N - mean*mean;
    float inv  = rsqrtf(var + 1e-5f);
    float sc   = gamma[c] * inv;
    bn[c]      = sc;
    bn[32 + c] = beta[c] - mean*sc;
  }
}

// Final: BN affine (layer 3) + linear_out
__global__ __launch_bounds__(256) void k_out(
    const float* __restrict__ z, const float* __restrict__ bn,
    const float* __restrict__ w_out, const float* __restrict__ b_out,
    float* __restrict__ out)
{
  __shared__ float a[32];
  __shared__ float c0s;
  const int tid = threadIdx.x;
  if (tid < 32) a[tid] = bn[tid] * w_out[tid];
  if (tid == 0) {
    float t = b_out[0];
    for (int c = 0; c < 32; ++c) t += bn[32 + c] * w_out[c];
    c0s = t;
  }
  __syncthreads();
  int gid = blockIdx.x*256 + tid;             // [0, 262144)
  int b = gid >> 14, pos = (gid & 16383) << 2;
  const float* zb = z + (long)b*2097152 + pos;
  float c0 = c0s;
  float r0 = c0, r1 = c0, r2 = c0, r3 = c0;
  #pragma unroll 8
  for (int c = 0; c < 32; ++c) {
    float4 v = *(const float4*)(zb + c*65536);
    float ac = a[c];
    r0 += v.x*ac; r1 += v.y*ac; r2 += v.z*ac; r3 += v.w*ac;
  }
  float4 res; res.x = r0; res.y = r1; res.z = r2; res.w = r3;
  *(float4*)(out + (long)b*65536 + pos) = res;
}

extern "C" void kernel_launch(void* const* d_in, const int* in_sizes, int n_in,
                              void* d_out, int out_size, void* d_ws, size_t ws_size,
                              hipStream_t stream) {
  const float* x      = (const float*)d_in[0];
  const float* coords = (const float*)d_in[1];
  const float* w_in   = (const float*)d_in[2];
  const float* b_in   = (const float*)d_in[3];
  const float* w1r    = (const float*)d_in[4];
  const float* w1i    = (const float*)d_in[5];
  const float* w2r    = (const float*)d_in[6];
  const float* w2i    = (const float*)d_in[7];
  const float* lw     = (const float*)d_in[8];
  const float* lb     = (const float*)d_in[9];
  const float* gamma  = (const float*)d_in[10];
  const float* beta   = (const float*)d_in[11];
  const float* w_out  = (const float*)d_in[12];
  const float* b_out  = (const float*)d_in[13];
  float* out = (float*)d_out;
  float* ws  = (float*)d_ws;

  float* cs   = ws;
  float* z    = cs + 512;            // gx aliases z[0:3145728]
  float* gx   = z;
  float* wf   = z + 3145728;         // fused weights alias z[3.1M:5.5M]
  float* gy   = z + 33554432;
  float* fc   = gy + 3145728;        // part aliases fc
  float* fm   = fc + 294912;
  float* bn   = fm + 294912;
  float* part = fc;

  k_init<<<1, 256, 0, stream>>>(cs);
  k_prep<<<1152, 256, 0, stream>>>(w1r, w1i, w2r, w2i, lw, wf);
  k_embed_fwd<<<4096, 256, 0, stream>>>(x, coords, w_in, b_in, cs, gx);

  for (int l = 0; l < 4; ++l) {
    k_fwd_y<<<768, 256, 0, stream>>>(gx, cs, (l == 0) ? nullptr : bn, fc);
    k_mix<<<288, 256, 0, stream>>>(fc, fm, wf + (long)l*589824);
    k_inv_y<<<192, 256, 0, stream>>>(fm, cs, gy);
    k_fuse<<<4096, 256, 0, stream>>>(gy, cs, lb + l*32,
                                     (l < 3) ? gx : nullptr, part,
                                     (l == 3) ? z : nullptr);
    k_stats<<<32, 256, 0, stream>>>(part, gamma + l*32, beta + l*32, bn);
  }

  k_out<<<1024, 256, 0, stream>>>(z, bn, w_out, b_out, out);
}

// Round 12
// 602.059 us; speedup vs baseline: 1.4661x; 1.1303x over previous
//
#include <hip/hip_runtime.h>

constexpr double PI2 = 6.283185307179586476925286766559;
constexpr float INV_HW = 1.0f / 65536.0f;

// B=16, D=32, H=W=256, M=12, L=4
// ws (floats), total 37,290,560 (142.25 MiB — proven safe):
//   cs[512] | z[33554432] | gy[3145728] | fc[294912] | fm[294912] | bn[64]
//   gx ALIASES z[0:3145728]; wf ALIASES z[3145728:5505024]; part ALIASES fc.
// gx layout: [b][y][ch32][mode24]; wf layout: [l][ky*12+kx][re1024|im1024].

__global__ __launch_bounds__(256) void k_init(float* __restrict__ cs) {
  int t = threadIdx.x;
  double a = PI2 * (double)t / 256.0;
  cs[2*t]   = (float)cos(a);
  cs[2*t+1] = (float)sin(a);
}

// Fold residual pointwise linear (I + lw) into the spectral mix weights:
// W'[i][o] = w[i][o] + sum_c w[i][c] * lw[o][c]
__global__ __launch_bounds__(256) void k_prep(
    const float* __restrict__ w1r, const float* __restrict__ w1i,
    const float* __restrict__ w2r, const float* __restrict__ w2i,
    const float* __restrict__ lw, float* __restrict__ wf)
{
  const int bid = blockIdx.x;
  const int l = bid / 288, m = bid % 288;
  const int ky = m / 12, kx = m % 12;
  const int kyp = (ky < 12) ? ky : ky - 12;
  const float* wr_ = ((ky < 12) ? w1r : w2r) + l*147456;
  const float* wi_ = ((ky < 12) ? w1i : w2i) + l*147456;
  __shared__ float wre[1024], wim[1024], lwl[1024];
  const int tid = threadIdx.x;
  for (int f = tid; f < 1024; f += 256) {
    int idx = f*144 + kyp*12 + kx;
    wre[f] = wr_[idx]; wim[f] = wi_[idx];
    lwl[f] = lw[l*1024 + f];
  }
  __syncthreads();
  float* o_ = wf + (long)bid*2048;
  for (int f = tid; f < 1024; f += 256) {
    int i = f >> 5, o = f & 31;
    float ar = wre[f], ai = wim[f];
    #pragma unroll
    for (int c = 0; c < 32; ++c) {
      float lv = lwl[o*32 + c];
      ar += wre[i*32 + c] * lv;
      ai += wim[i*32 + c] * lv;
    }
    o_[f] = ar; o_[1024 + f] = ai;
  }
}

// Layer-0: h0 in registers -> x-DFT (even/odd real-input form) -> gx
__global__ __launch_bounds__(256) void k_embed_fwd(
    const float* __restrict__ xin, const float* __restrict__ coords,
    const float* __restrict__ w_in, const float* __restrict__ b_in,
    const float* __restrict__ cs, float* __restrict__ gxo)
{
  __shared__ float wl[96], bl[32];
  __shared__ __align__(16) float csl[512];
  __shared__ float S[32*257];
  const int tid = threadIdx.x;
  if (tid < 96) wl[tid] = w_in[tid];
  if (tid >= 96 && tid < 128) bl[tid-96] = b_in[tid-96];
  for (int f = tid; f < 512; f += 256) csl[f] = cs[f];
  const int b = blockIdx.x >> 8, y = blockIdx.x & 255;
  const float xv = xin[(b*256 + y)*256 + tid];
  const float c0 = coords[y*256 + tid];
  const float c1 = coords[65536 + y*256 + tid];
  __syncthreads();
  #pragma unroll 8
  for (int d = 0; d < 32; ++d)
    S[d*257 + tid] = wl[3*d]*xv + wl[3*d+1]*c0 + wl[3*d+2]*c1 + bl[d];
  __syncthreads();
  const int task = tid >> 5, o = tid & 31;
  if (task < 6) {
    const int kx0 = task*2, kx1 = kx0 + 1;   // kx0 even, kx1 odd
    const float* Sp = &S[o*257];
    const float s0v = Sp[0], s128 = Sp[128];
    float ar0 = s0v + s128, ai0 = 0.f;
    float ar1 = s0v - s128, ai1 = 0.f;
    int t0 = kx0, t1 = kx1;                  // angle index at x=1
    for (int xx = 1; xx < 128; ++xx) {
      float a = Sp[xx], bv = Sp[256 - xx];
      float e = a + bv, od = a - bv;
      float2 w0 = *(const float2*)&csl[2*t0];
      float2 w1 = *(const float2*)&csl[2*t1];
      ar0 += e*w0.x;  ai0 -= od*w0.y;
      ar1 += e*w1.x;  ai1 -= od*w1.y;
      t0 = (t0 + kx0) & 255;
      t1 = (t1 + kx1) & 255;
    }
    float4 w4; w4.x = ar0; w4.y = ai0; w4.z = ar1; w4.w = ai1;
    *(float4*)(gxo + ((long)(b*256 + y)*32 + o)*24 + task*4) = w4;
  }
}

// Forward DFT along y with BN-affine fold on staging.
// Mirror-mode symmetry: X[ky] and X[256-ky] share one accumulator pass.
// 26 lanes = 13 tasks x 2 y-halves; shfl combine.
// Reads gx[b][y][ch][mode]; fc layout [b][ky24][kx12][C32][2]
__global__ __launch_bounds__(256) void k_fwd_y(
    const float* __restrict__ gx, const float* __restrict__ cs,
    const float* __restrict__ bnp, float* __restrict__ fc)
{
  __shared__ __align__(16) float R[8*528];
  __shared__ __align__(16) float csl[512];
  const int tid = threadIdx.x;
  for (int f = tid; f < 512; f += 256) csl[f] = cs[f];
  const int g = tid >> 5, s = tid & 31;
  const int task = blockIdx.x*8 + g;        // [0, 6144)
  const int bc = task / 12, kx = task % 12;
  const int bb = bc >> 5, ch = bc & 31;
  {
    const float* rr = gx + ((long)(bb*256)*32 + ch)*24 + 2*kx;  // + y*768
    float sc = 1.0f, badd = 0.0f;
    if (bnp) {
      sc = bnp[ch];
      badd = (kx == 0) ? 256.0f*bnp[32 + ch] : 0.0f;
    }
    for (int i = 0; i < 8; ++i) {          // 32 lanes x 8 = 256 y
      int y = s + 32*i;
      float2 v = *(const float2*)(rr + (long)y*768);
      R[g*528 + 2*y]     = sc*v.x + badd;
      R[g*528 + 2*y + 1] = sc*v.y;
    }
  }
  __syncthreads();
  if (s < 26) {
    // task list: pr 0..10 -> mode pair (ky=pr+1, 256-(pr+1)); pr 11 -> ky=0;
    // pr 12 -> ky=244. hf = which y-half this lane accumulates.
    const int pr = s >> 1, hf = s & 1;
    const int kyv = (pr <= 10) ? (pr + 1) : ((pr == 11) ? 0 : 244);
    const int y0 = hf << 7;
    int tt = (kyv * y0) & 255;
    float A = 0.f, Bv = 0.f, C2 = 0.f, D = 0.f;
    const float* Rg = &R[g*528 + 2*y0];
    for (int i = 0; i < 128; ++i) {
      float2 v = *(const float2*)&Rg[2*i];
      float2 w = *(const float2*)&csl[2*tt];
      A  += v.x*w.x;  D  += v.x*w.y;
      C2 += v.y*w.x;  Bv += v.y*w.y;
      tt = (tt + kyv) & 255;
    }
    A  += __shfl_xor(A, 1, 64);
    Bv += __shfl_xor(Bv, 1, 64);
    C2 += __shfl_xor(C2, 1, 64);
    D  += __shfl_xor(D, 1, 64);
    if (hf == 0) {
      // X[kyv] = (A+Bv, C2-D); X[256-kyv] = (A-Bv, C2+D)
      const int slo = (pr <= 10) ? (pr + 1) : ((pr == 11) ? 0 : 12);
      float* o1 = fc + ((bb*24 + slo)*12 + kx)*64 + 2*ch;
      o1[0] = A + Bv; o1[1] = C2 - D;
      if (pr <= 10) {
        float* o2 = fc + ((bb*24 + (23 - pr))*12 + kx)*64 + 2*ch;
        o2[0] = A - Bv; o2[1] = C2 + D;
      }
    }
  }
}

// Per-mode complex channel mix with pre-folded weights.
__global__ __launch_bounds__(256) void k_mix(
    const float* __restrict__ fc, float* __restrict__ fm,
    const float* __restrict__ wfl)
{
  const int ky = blockIdx.x / 12, kx = blockIdx.x % 12;
  const int tid = threadIdx.x;
  __shared__ float wre[1024], wim[1024];
  __shared__ float fin[1024];
  const float* wb = wfl + (long)blockIdx.x*2048;
  for (int f = tid; f < 1024; f += 256) {
    wre[f] = wb[f];
    wim[f] = wb[1024 + f];
  }
  for (int f = tid; f < 1024; f += 256) {
    int b = f >> 6, j = f & 63;
    fin[f] = fc[((b*24 + ky)*12 + kx)*64 + j];
  }
  __syncthreads();
  for (int k = 0; k < 2; ++k) {
    int idx = tid + k*256;
    int b = idx >> 5, o = idx & 31;
    float ar = 0.f, ai = 0.f;
    #pragma unroll
    for (int i = 0; i < 32; ++i) {
      float fr = fin[b*64 + 2*i], fi2 = fin[b*64 + 2*i + 1];
      float wr = wre[i*32+o],     wi2 = wim[i*32+o];
      ar += fr*wr - fi2*wi2;
      ai += fr*wi2 + fi2*wr;
    }
    float* op = fm + ((b*24 + ky)*12 + kx)*64 + 2*o;
    op[0] = ar; op[1] = ai;
  }
}

// Inverse DFT along y: 24 modes -> 256 y. gy layout [b][y][kx][o][2]
__global__ __launch_bounds__(256) void k_inv_y(
    const float* __restrict__ fm, const float* __restrict__ cs,
    float* __restrict__ gy)
{
  const int b = blockIdx.x / 12, kx = blockIdx.x % 12;
  const int tid = threadIdx.x;
  __shared__ __align__(16) float F[1536];
  __shared__ __align__(16) float csl[512];
  for (int f = tid; f < 1536; f += 256) {
    int s = f >> 6, j = f & 63;
    F[f] = fm[((b*24 + s)*12 + kx)*64 + j];
  }
  for (int f = tid; f < 512; f += 256) csl[f] = cs[f];
  __syncthreads();
  const int y = tid;
  float tc[24], tsn[24];
  #pragma unroll
  for (int s = 0; s < 24; ++s) {
    int kyv = (s < 12) ? s : (232 + s);
    int tt = (kyv * y) & 255;
    tc[s] = csl[2*tt]; tsn[s] = csl[2*tt+1];
  }
  float* orow = gy + ((b*256 + y)*12 + kx)*64;
  for (int o2 = 0; o2 < 16; ++o2) {
    float ar0 = 0.f, ai0 = 0.f, ar1 = 0.f, ai1 = 0.f;
    #pragma unroll
    for (int s = 0; s < 24; ++s) {
      float2 f0 = *(const float2*)&F[s*64 + 4*o2];
      float2 f1 = *(const float2*)&F[s*64 + 4*o2 + 2];
      ar0 += f0.x*tc[s] - f0.y*tsn[s];
      ai0 += f0.x*tsn[s] + f0.y*tc[s];
      ar1 += f1.x*tc[s] - f1.y*tsn[s];
      ai1 += f1.x*tsn[s] + f1.y*tc[s];
    }
    float4 v;
    v.x = ar0*INV_HW; v.y = ai0*INV_HW; v.z = ar1*INV_HW; v.w = ai1*INV_HW;
    *(float4*)(orow + 4*o2) = v;
  }
}

// FUSED: inverse-x c2r (x-mirror symmetric: thread -> {xs, 256-xs} x 16 ch)
// + lb + relu + BN partials + next layer's forward-x DFT (even/odd).
__global__ __launch_bounds__(256) void k_fuse(
    const float* __restrict__ gy, const float* __restrict__ cs,
    const float* __restrict__ lb,
    float* __restrict__ gxo, float* __restrict__ part, float* __restrict__ z)
{
  const int b = blockIdx.x >> 8, y = blockIdx.x & 255;
  const int tid = threadIdx.x;
  __shared__ __align__(16) float csl[512];
  __shared__ float S[32*257];
  for (int f = tid; f < 512; f += 256) csl[f] = cs[f];
  __syncthreads();
  // phase A: thread (xs, half) computes z at x=xs and x=256-xs for 16 ch.
  // half = tid>>7 is wave-uniform -> Gg loads stay scalar.
  const int xs = tid & 127, half = tid >> 7;
  const int cbase = half << 4;
  const int xhi = (256 - xs) & 255;            // xs==0 -> 0 (dup write, benign)
  float tc[12], tsn[12];
  #pragma unroll
  for (int kx = 1; kx < 12; ++kx) {
    int tt = (kx * xs) & 255;
    tc[kx]  = 2.0f*csl[2*tt];
    tsn[kx] = 2.0f*csl[2*tt+1];                // xs==0 -> 0 (zlo==zhi==z[0])
  }
  const float* Gg = gy + (long)(b*256 + y)*768;   // wave-uniform base
  float zlo[16], zhi[16];
  #pragma unroll
  for (int cc = 0; cc < 16; cc += 2) {
    const int c = cbase + cc;
    float base0 = Gg[2*c], base1 = Gg[2*c + 2];
    float cos0 = 0.f, sin0 = 0.f, cos1 = 0.f, sin1 = 0.f;
    #pragma unroll
    for (int kx = 1; kx < 12; ++kx) {
      float4 g = *(const float4*)(Gg + kx*64 + 2*c);
      cos0 += g.x*tc[kx];  sin0 += g.y*tsn[kx];
      cos1 += g.z*tc[kx];  sin1 += g.w*tsn[kx];
    }
    const float l0 = lb[c], l1 = lb[c+1];
    zlo[cc]   = fmaxf(base0 + cos0 - sin0 + l0, 0.f);
    zhi[cc]   = fmaxf(base0 + cos0 + sin0 + l0, 0.f);
    zlo[cc+1] = fmaxf(base1 + cos1 - sin1 + l1, 0.f);
    zhi[cc+1] = fmaxf(base1 + cos1 + sin1 + l1, 0.f);
  }
  #pragma unroll
  for (int cc = 0; cc < 16; ++cc) {
    S[(cbase+cc)*257 + xs]  = zlo[cc];
    S[(cbase+cc)*257 + xhi] = zhi[cc];
  }
  if (z) {
    #pragma unroll
    for (int cc = 0; cc < 16; ++cc) {
      z[((b*32 + cbase+cc)*256 + y)*256 + xs]  = zlo[cc];
      z[((b*32 + cbase+cc)*256 + y)*256 + xhi] = zhi[cc];
    }
  }
  // x=128 fixup: lane = channel; sin terms vanish, cos = 2*(-1)^kx.
  if (tid < 32) {
    const int c = tid;
    float acc = Gg[2*c] + lb[c];
    #pragma unroll
    for (int kx = 1; kx < 12; ++kx) {
      float2 g = *(const float2*)(Gg + kx*64 + 2*c);
      acc += (kx & 1) ? (-2.0f * g.x) : (2.0f * g.x);
    }
    float zv = fmaxf(acc, 0.f);
    S[c*257 + 128] = zv;
    if (z) z[((b*32 + c)*256 + y)*256 + 128] = zv;
  }
  __syncthreads();
  // phase B: real-input DFT via even/odd halves. tasks 0-5: mode pairs;
  // task0's kx=0 real part doubles as the BN sum; tasks 6,7: sumsq halves.
  const int task = tid >> 5, o = tid & 31;
  if (task < 6) {
    if (gxo || task == 0) {
      const int kx0 = task*2, kx1 = kx0 + 1;   // kx0 even, kx1 odd
      const float* Sp = &S[o*257];
      const float s0v = Sp[0], s128 = Sp[128];
      float ar0 = s0v + s128, ai0 = 0.f;       // cos(pi*kx0) = +1
      float ar1 = s0v - s128, ai1 = 0.f;       // cos(pi*kx1) = -1
      int t0 = kx0, t1 = kx1;                  // angle index at x=1
      for (int xx = 1; xx < 128; ++xx) {
        float a = Sp[xx], bv = Sp[256 - xx];
        float e = a + bv, od = a - bv;
        float2 w0 = *(const float2*)&csl[2*t0];
        float2 w1 = *(const float2*)&csl[2*t1];
        ar0 += e*w0.x;  ai0 -= od*w0.y;
        ar1 += e*w1.x;  ai1 -= od*w1.y;
        t0 = (t0 + kx0) & 255;
        t1 = (t1 + kx1) & 255;
      }
      if (task == 0) part[(long)blockIdx.x*64 + 2*o] = ar0;   // channel sum
      if (gxo) {
        float4 w4; w4.x = ar0; w4.y = ai0; w4.z = ar1; w4.w = ai1;
        *(float4*)(gxo + ((long)(b*256 + y)*32 + o)*24 + task*4) = w4;
      }
    }
  } else {
    const int xb = (task - 6) << 7;
    const float* Sp = &S[o*257];
    float sq = 0.f;
    for (int j = 0; j < 128; ++j) { float v = Sp[xb + j]; sq += v*v; }
    sq += __shfl_xor(sq, 32, 64);          // combine task6+task7 (same wave)
    if (task == 6) part[(long)blockIdx.x*64 + 2*o + 1] = sq;
  }
}

// Reduce partials -> BN scale/bias for next consumer
__global__ __launch_bounds__(256) void k_stats(
    const float* __restrict__ part, const float* __restrict__ gamma,
    const float* __restrict__ beta, float* __restrict__ bn)
{
  const int c = blockIdx.x, tid = threadIdx.x;
  float s1 = 0.f, s2 = 0.f;
  for (int j = tid; j < 4096; j += 256) {
    s1 += part[(long)j*64 + 2*c];
    s2 += part[(long)j*64 + 2*c + 1];
  }
  #pragma unroll
  for (int d = 32; d; d >>= 1) {
    s1 += __shfl_xor(s1, d, 64);
    s2 += __shfl_xor(s2, d, 64);
  }
  __shared__ float r1[4], r2[4];
  int w = tid >> 6;
  if ((tid & 63) == 0) { r1[w] = s1; r2[w] = s2; }
  __syncthreads();
  if (tid == 0) {
    float S1 = r1[0]+r1[1]+r1[2]+r1[3];
    float S2 = r2[0]+r2[1]+r2[2]+r2[3];
    const float N = 1048576.0f;
    float mean = S1 / N;
    float var  = S2 / N - mean*mean;
    float inv  = rsqrtf(var + 1e-5f);
    float sc   = gamma[c] * inv;
    bn[c]      = sc;
    bn[32 + c] = beta[c] - mean*sc;
  }
}

// Final: BN affine (layer 3) + linear_out
__global__ __launch_bounds__(256) void k_out(
    const float* __restrict__ z, const float* __restrict__ bn,
    const float* __restrict__ w_out, const float* __restrict__ b_out,
    float* __restrict__ out)
{
  __shared__ float a[32];
  __shared__ float c0s;
  const int tid = threadIdx.x;
  if (tid < 32) a[tid] = bn[tid] * w_out[tid];
  if (tid == 0) {
    float t = b_out[0];
    for (int c = 0; c < 32; ++c) t += bn[32 + c] * w_out[c];
    c0s = t;
  }
  __syncthreads();
  int gid = blockIdx.x*256 + tid;             // [0, 262144)
  int b = gid >> 14, pos = (gid & 16383) << 2;
  const float* zb = z + (long)b*2097152 + pos;
  float c0 = c0s;
  float r0 = c0, r1 = c0, r2 = c0, r3 = c0;
  #pragma unroll 8
  for (int c = 0; c < 32; ++c) {
    float4 v = *(const float4*)(zb + c*65536);
    float ac = a[c];
    r0 += v.x*ac; r1 += v.y*ac; r2 += v.z*ac; r3 += v.w*ac;
  }
  float4 res; res.x = r0; res.y = r1; res.z = r2; res.w = r3;
  *(float4*)(out + (long)b*65536 + pos) = res;
}

extern "C" void kernel_launch(void* const* d_in, const int* in_sizes, int n_in,
                              void* d_out, int out_size, void* d_ws, size_t ws_size,
                              hipStream_t stream) {
  const float* x      = (const float*)d_in[0];
  const float* coords = (const float*)d_in[1];
  const float* w_in   = (const float*)d_in[2];
  const float* b_in   = (const float*)d_in[3];
  const float* w1r    = (const float*)d_in[4];
  const float* w1i    = (const float*)d_in[5];
  const float* w2r    = (const float*)d_in[6];
  const float* w2i    = (const float*)d_in[7];
  const float* lw     = (const float*)d_in[8];
  const float* lb     = (const float*)d_in[9];
  const float* gamma  = (const float*)d_in[10];
  const float* beta   = (const float*)d_in[11];
  const float* w_out  = (const float*)d_in[12];
  const float* b_out  = (const float*)d_in[13];
  float* out = (float*)d_out;
  float* ws  = (float*)d_ws;

  float* cs   = ws;
  float* z    = cs + 512;            // gx aliases z[0:3145728]
  float* gx   = z;
  float* wf   = z + 3145728;         // fused weights alias z[3.1M:5.5M]
  float* gy   = z + 33554432;
  float* fc   = gy + 3145728;        // part aliases fc
  float* fm   = fc + 294912;
  float* bn   = fm + 294912;
  float* part = fc;

  k_init<<<1, 256, 0, stream>>>(cs);
  k_prep<<<1152, 256, 0, stream>>>(w1r, w1i, w2r, w2i, lw, wf);
  k_embed_fwd<<<4096, 256, 0, stream>>>(x, coords, w_in, b_in, cs, gx);

  for (int l = 0; l < 4; ++l) {
    k_fwd_y<<<768, 256, 0, stream>>>(gx, cs, (l == 0) ? nullptr : bn, fc);
    k_mix<<<288, 256, 0, stream>>>(fc, fm, wf + (long)l*589824);
    k_inv_y<<<192, 256, 0, stream>>>(fm, cs, gy);
    k_fuse<<<4096, 256, 0, stream>>>(gy, cs, lb + l*32,
                                     (l < 3) ? gx : nullptr, part,
                                     (l == 3) ? z : nullptr);
    k_stats<<<32, 256, 0, stream>>>(part, gamma + l*32, beta + l*32, bn);
  }

  k_out<<<1024, 256, 0, stream>>>(z, bn, w_out, b_out, out);
}

// Round 13
// 541.264 us; speedup vs baseline: 1.6308x; 1.1123x over previous
//
#include <hip/hip_runtime.h>

constexpr double PI2 = 6.283185307179586476925286766559;
constexpr float INV_HW = 1.0f / 65536.0f;

// B=16, D=32, H=W=256, M=12, L=4
// ws (floats), total 37,290,560 (142.25 MiB — proven safe):
//   cs[512] | z[33554432] | gy[3145728] | fc[294912] | fm[294912] | bn[64]
//   gx ALIASES z[0:3145728]; wf ALIASES z[3145728:5505024]; part ALIASES fc.
// gx layout: [b][y][ch32][mode24]; wf layout: [l][ky*12+kx][re1024|im1024].

__global__ __launch_bounds__(256) void k_init(float* __restrict__ cs) {
  int t = threadIdx.x;
  double a = PI2 * (double)t / 256.0;
  cs[2*t]   = (float)cos(a);
  cs[2*t+1] = (float)sin(a);
}

// Fold residual pointwise linear (I + lw) into the spectral mix weights:
// W'[i][o] = w[i][o] + sum_c w[i][c] * lw[o][c]
__global__ __launch_bounds__(256) void k_prep(
    const float* __restrict__ w1r, const float* __restrict__ w1i,
    const float* __restrict__ w2r, const float* __restrict__ w2i,
    const float* __restrict__ lw, float* __restrict__ wf)
{
  const int bid = blockIdx.x;
  const int l = bid / 288, m = bid % 288;
  const int ky = m / 12, kx = m % 12;
  const int kyp = (ky < 12) ? ky : ky - 12;
  const float* wr_ = ((ky < 12) ? w1r : w2r) + l*147456;
  const float* wi_ = ((ky < 12) ? w1i : w2i) + l*147456;
  __shared__ float wre[1024], wim[1024], lwl[1024];
  const int tid = threadIdx.x;
  for (int f = tid; f < 1024; f += 256) {
    int idx = f*144 + kyp*12 + kx;
    wre[f] = wr_[idx]; wim[f] = wi_[idx];
    lwl[f] = lw[l*1024 + f];
  }
  __syncthreads();
  float* o_ = wf + (long)bid*2048;
  for (int f = tid; f < 1024; f += 256) {
    int i = f >> 5, o = f & 31;
    float ar = wre[f], ai = wim[f];
    #pragma unroll
    for (int c = 0; c < 32; ++c) {
      float lv = lwl[o*32 + c];
      ar += wre[i*32 + c] * lv;
      ai += wim[i*32 + c] * lv;
    }
    o_[f] = ar; o_[1024 + f] = ai;
  }
}

// Layer-0: h0 in registers -> x-DFT (even/odd real-input form) -> gx
__global__ __launch_bounds__(256) void k_embed_fwd(
    const float* __restrict__ xin, const float* __restrict__ coords,
    const float* __restrict__ w_in, const float* __restrict__ b_in,
    const float* __restrict__ cs, float* __restrict__ gxo)
{
  __shared__ float wl[96], bl[32];
  __shared__ __align__(16) float csl[512];
  __shared__ float S[32*257];
  const int tid = threadIdx.x;
  if (tid < 96) wl[tid] = w_in[tid];
  if (tid >= 96 && tid < 128) bl[tid-96] = b_in[tid-96];
  for (int f = tid; f < 512; f += 256) csl[f] = cs[f];
  const int b = blockIdx.x >> 8, y = blockIdx.x & 255;
  const float xv = xin[(b*256 + y)*256 + tid];
  const float c0 = coords[y*256 + tid];
  const float c1 = coords[65536 + y*256 + tid];
  __syncthreads();
  #pragma unroll 8
  for (int d = 0; d < 32; ++d)
    S[d*257 + tid] = wl[3*d]*xv + wl[3*d+1]*c0 + wl[3*d+2]*c1 + bl[d];
  __syncthreads();
  const int task = tid >> 5, o = tid & 31;
  if (task < 6) {
    const int kx0 = task*2, kx1 = kx0 + 1;   // kx0 even, kx1 odd
    const float* Sp = &S[o*257];
    const float s0v = Sp[0], s128 = Sp[128];
    float ar0 = s0v + s128, ai0 = 0.f;
    float ar1 = s0v - s128, ai1 = 0.f;
    int t0 = kx0, t1 = kx1;                  // angle index at x=1
    for (int xx = 1; xx < 128; ++xx) {
      float a = Sp[xx], bv = Sp[256 - xx];
      float e = a + bv, od = a - bv;
      float2 w0 = *(const float2*)&csl[2*t0];
      float2 w1 = *(const float2*)&csl[2*t1];
      ar0 += e*w0.x;  ai0 -= od*w0.y;
      ar1 += e*w1.x;  ai1 -= od*w1.y;
      t0 = (t0 + kx0) & 255;
      t1 = (t1 + kx1) & 255;
    }
    float4 w4; w4.x = ar0; w4.y = ai0; w4.z = ar1; w4.w = ai1;
    *(float4*)(gxo + ((long)(b*256 + y)*32 + o)*24 + task*4) = w4;
  }
}

// FUSED SPECTRAL: fwd-y DFT (mirror pairs) + channel mix + inv-y DFT
// (y-mirror pairs). block = (b,kx) XCD-swizzled, 512 threads.
// Reads gx[b][y][ch][mode] (BN fold on staging); writes gy[b][y][kx][o][2].
__global__ __launch_bounds__(512) void k_spec(
    const float* __restrict__ gx, const float* __restrict__ cs,
    const float* __restrict__ bnp, const float* __restrict__ wfl,
    float* __restrict__ gy)
{
  const int bid = (blockIdx.x % 8) * 24 + blockIdx.x / 8;  // XCD swizzle (192=8*24)
  const int b = bid / 12, kx = bid % 12;
  __shared__ float2 Z[32*257];           // [ch][y], pad 257 (2-way max)
  __shared__ float fcl[24*66];           // [ky][ch][2], row pad 66
  __shared__ float fml[24*66];           // [ky][o][2]
  __shared__ __align__(16) float csl[512];
  const int tid = threadIdx.x;
  if (tid < 512) csl[tid] = cs[tid];
  // stage 32x256 float2 slice with BN-affine fold (ch = tid&31 constant)
  {
    const int ch = tid & 31;
    float sc = 1.0f, badd = 0.0f;
    if (bnp) { sc = bnp[ch]; if (kx == 0) badd = 256.0f * bnp[32 + ch]; }
    const float* src = gx + ((long)(b*256)*32 + ch)*24 + 2*kx;
    const int ybase = tid >> 5;          // 0..15
    #pragma unroll
    for (int i = 0; i < 16; ++i) {
      int y = ybase + 16*i;
      float2 v = *(const float2*)(src + (long)y*768);
      float2 w; w.x = sc*v.x + badd; w.y = sc*v.y;
      Z[ch*257 + y] = w;
    }
  }
  __syncthreads();
  // fwd_y: 832 half-tasks = 32ch x 13 mode-pairs x 2 y-halves
  for (int t = tid; t < 832; t += 512) {
    const int hf = t & 1, r = t >> 1;
    const int pr = r % 13, ch = r / 13;
    const int kyv = (pr <= 10) ? (pr + 1) : ((pr == 11) ? 0 : 244);
    const int y0 = hf << 7;
    int tt = (kyv * y0) & 255;
    float A = 0.f, Bv = 0.f, C2 = 0.f, D = 0.f;
    const float2* Zp = &Z[ch*257 + y0];
    for (int i = 0; i < 128; ++i) {
      float2 v = Zp[i];
      float2 w = *(const float2*)&csl[2*tt];
      A  += v.x*w.x;  D  += v.x*w.y;
      C2 += v.y*w.x;  Bv += v.y*w.y;
      tt = (tt + kyv) & 255;
    }
    A  += __shfl_xor(A, 1, 64);
    Bv += __shfl_xor(Bv, 1, 64);
    C2 += __shfl_xor(C2, 1, 64);
    D  += __shfl_xor(D, 1, 64);
    if (hf == 0) {
      // X[kyv] = (A+Bv, C2-D); X[256-kyv] = (A-Bv, C2+D)
      const int slo = (pr <= 10) ? (pr + 1) : ((pr == 11) ? 0 : 12);
      fcl[slo*66 + 2*ch]     = A + Bv;
      fcl[slo*66 + 2*ch + 1] = C2 - D;
      if (pr <= 10) {
        fcl[(23 - pr)*66 + 2*ch]     = A - Bv;
        fcl[(23 - pr)*66 + 2*ch + 1] = C2 + D;
      }
    }
  }
  __syncthreads();
  // mix: 768 complex outs (24ky x 32o); weights from L2
  for (int t = tid; t < 768; t += 512) {
    const int ky = t >> 5, o = t & 31;
    const float* wb = wfl + ((long)(ky*12 + kx))*2048;
    const float* fr = &fcl[ky*66];
    float ar = 0.f, ai = 0.f;
    #pragma unroll
    for (int i = 0; i < 32; ++i) {
      float fre = fr[2*i], fim = fr[2*i+1];
      float wr = wb[i*32 + o], wi = wb[1024 + i*32 + o];
      ar += fre*wr - fim*wi;
      ai += fre*wi + fim*wr;
    }
    fml[ky*66 + 2*o]     = ar;
    fml[ky*66 + 2*o + 1] = ai;
  }
  __syncthreads();
  // inv_y with y-mirror: thread (yp = tid&127, og = tid>>7), 8 o's each.
  {
    const int yp = tid & 127, og = tid >> 7;
    float tc[24], tsn[24];
    #pragma unroll
    for (int s = 0; s < 24; ++s) {
      int kyv = (s < 12) ? s : (232 + s);
      int tt = (kyv * yp) & 255;
      tc[s] = csl[2*tt]; tsn[s] = csl[2*tt+1];
    }
    const int yhi = (256 - yp) & 255;    // yp==0 -> dup write, benign
    float* rowLo = gy + ((long)(b*256 + yp))*768 + kx*64;
    float* rowHi = gy + ((long)(b*256 + yhi))*768 + kx*64;
    #pragma unroll
    for (int oo = 0; oo < 8; oo += 2) {
      const int o = og*8 + oo;
      float A1a=0.f,A2a=0.f,A3a=0.f,A4a=0.f;
      float A1b=0.f,A2b=0.f,A3b=0.f,A4b=0.f;
      #pragma unroll
      for (int s = 0; s < 24; ++s) {
        float fra = fml[s*66 + 2*o],     fia = fml[s*66 + 2*o + 1];
        float frb = fml[s*66 + 2*o + 2], fib = fml[s*66 + 2*o + 3];
        float c = tc[s], sn = tsn[s];
        A1a += fra*c;  A2a += fia*sn;  A3a += fra*sn;  A4a += fia*c;
        A1b += frb*c;  A2b += fib*sn;  A3b += frb*sn;  A4b += fib*c;
      }
      float4 lo, hi;
      lo.x = (A1a - A2a)*INV_HW; lo.y = (A3a + A4a)*INV_HW;
      lo.z = (A1b - A2b)*INV_HW; lo.w = (A3b + A4b)*INV_HW;
      hi.x = (A1a + A2a)*INV_HW; hi.y = (A4a - A3a)*INV_HW;
      hi.z = (A1b + A2b)*INV_HW; hi.w = (A4b - A3b)*INV_HW;
      *(float4*)(rowLo + 2*o) = lo;
      *(float4*)(rowHi + 2*o) = hi;
    }
  }
  // y = 128 singleton: cos = (-1)^kyv (parity of s), sin = 0
  if (tid < 32) {
    const int o = tid;
    float re = 0.f, im = 0.f;
    #pragma unroll
    for (int s = 0; s < 24; ++s) {
      float fr = fml[s*66 + 2*o], fi = fml[s*66 + 2*o + 1];
      if (s & 1) { re -= fr; im -= fi; } else { re += fr; im += fi; }
    }
    float* row = gy + ((long)(b*256 + 128))*768 + kx*64;
    row[2*o]     = re*INV_HW;
    row[2*o + 1] = im*INV_HW;
  }
}

// FUSED: inverse-x c2r (x-mirror symmetric: thread -> {xs, 256-xs} x 16 ch)
// + lb + relu + BN partials + next layer's forward-x DFT (even/odd).
__global__ __launch_bounds__(256) void k_fuse(
    const float* __restrict__ gy, const float* __restrict__ cs,
    const float* __restrict__ lb,
    float* __restrict__ gxo, float* __restrict__ part, float* __restrict__ z)
{
  const int b = blockIdx.x >> 8, y = blockIdx.x & 255;
  const int tid = threadIdx.x;
  __shared__ __align__(16) float csl[512];
  __shared__ float S[32*257];
  for (int f = tid; f < 512; f += 256) csl[f] = cs[f];
  __syncthreads();
  const int xs = tid & 127, half = tid >> 7;
  const int cbase = half << 4;
  const int xhi = (256 - xs) & 255;
  float tc[12], tsn[12];
  #pragma unroll
  for (int kx = 1; kx < 12; ++kx) {
    int tt = (kx * xs) & 255;
    tc[kx]  = 2.0f*csl[2*tt];
    tsn[kx] = 2.0f*csl[2*tt+1];
  }
  const float* Gg = gy + (long)(b*256 + y)*768;   // wave-uniform base
  float zlo[16], zhi[16];
  #pragma unroll
  for (int cc = 0; cc < 16; cc += 2) {
    const int c = cbase + cc;
    float base0 = Gg[2*c], base1 = Gg[2*c + 2];
    float cos0 = 0.f, sin0 = 0.f, cos1 = 0.f, sin1 = 0.f;
    #pragma unroll
    for (int kx = 1; kx < 12; ++kx) {
      float4 g = *(const float4*)(Gg + kx*64 + 2*c);
      cos0 += g.x*tc[kx];  sin0 += g.y*tsn[kx];
      cos1 += g.z*tc[kx];  sin1 += g.w*tsn[kx];
    }
    const float l0 = lb[c], l1 = lb[c+1];
    zlo[cc]   = fmaxf(base0 + cos0 - sin0 + l0, 0.f);
    zhi[cc]   = fmaxf(base0 + cos0 + sin0 + l0, 0.f);
    zlo[cc+1] = fmaxf(base1 + cos1 - sin1 + l1, 0.f);
    zhi[cc+1] = fmaxf(base1 + cos1 + sin1 + l1, 0.f);
  }
  #pragma unroll
  for (int cc = 0; cc < 16; ++cc) {
    S[(cbase+cc)*257 + xs]  = zlo[cc];
    S[(cbase+cc)*257 + xhi] = zhi[cc];
  }
  if (z) {
    #pragma unroll
    for (int cc = 0; cc < 16; ++cc) {
      z[((b*32 + cbase+cc)*256 + y)*256 + xs]  = zlo[cc];
      z[((b*32 + cbase+cc)*256 + y)*256 + xhi] = zhi[cc];
    }
  }
  // x=128 fixup: lane = channel; sin terms vanish, cos = 2*(-1)^kx.
  if (tid < 32) {
    const int c = tid;
    float acc = Gg[2*c] + lb[c];
    #pragma unroll
    for (int kx = 1; kx < 12; ++kx) {
      float2 g = *(const float2*)(Gg + kx*64 + 2*c);
      acc += (kx & 1) ? (-2.0f * g.x) : (2.0f * g.x);
    }
    float zv = fmaxf(acc, 0.f);
    S[c*257 + 128] = zv;
    if (z) z[((b*32 + c)*256 + y)*256 + 128] = zv;
  }
  __syncthreads();
  // phase B: real-input DFT via even/odd halves. tasks 0-5: mode pairs;
  // task0's kx=0 real part doubles as the BN sum; tasks 6,7: sumsq halves.
  const int task = tid >> 5, o = tid & 31;
  if (task < 6) {
    if (gxo || task == 0) {
      const int kx0 = task*2, kx1 = kx0 + 1;   // kx0 even, kx1 odd
      const float* Sp = &S[o*257];
      const float s0v = Sp[0], s128 = Sp[128];
      float ar0 = s0v + s128, ai0 = 0.f;       // cos(pi*kx0) = +1
      float ar1 = s0v - s128, ai1 = 0.f;       // cos(pi*kx1) = -1
      int t0 = kx0, t1 = kx1;                  // angle index at x=1
      for (int xx = 1; xx < 128; ++xx) {
        float a = Sp[xx], bv = Sp[256 - xx];
        float e = a + bv, od = a - bv;
        float2 w0 = *(const float2*)&csl[2*t0];
        float2 w1 = *(const float2*)&csl[2*t1];
        ar0 += e*w0.x;  ai0 -= od*w0.y;
        ar1 += e*w1.x;  ai1 -= od*w1.y;
        t0 = (t0 + kx0) & 255;
        t1 = (t1 + kx1) & 255;
      }
      if (task == 0) part[(long)blockIdx.x*64 + 2*o] = ar0;   // channel sum
      if (gxo) {
        float4 w4; w4.x = ar0; w4.y = ai0; w4.z = ar1; w4.w = ai1;
        *(float4*)(gxo + ((long)(b*256 + y)*32 + o)*24 + task*4) = w4;
      }
    }
  } else {
    const int xb = (task - 6) << 7;
    const float* Sp = &S[o*257];
    float sq = 0.f;
    for (int j = 0; j < 128; ++j) { float v = Sp[xb + j]; sq += v*v; }
    sq += __shfl_xor(sq, 32, 64);          // combine task6+task7 (same wave)
    if (task == 6) part[(long)blockIdx.x*64 + 2*o + 1] = sq;
  }
}

// Reduce partials -> BN scale/bias for next consumer
__global__ __launch_bounds__(256) void k_stats(
    const float* __restrict__ part, const float* __restrict__ gamma,
    const float* __restrict__ beta, float* __restrict__ bn)
{
  const int c = blockIdx.x, tid = threadIdx.x;
  float s1 = 0.f, s2 = 0.f;
  for (int j = tid; j < 4096; j += 256) {
    s1 += part[(long)j*64 + 2*c];
    s2 += part[(long)j*64 + 2*c + 1];
  }
  #pragma unroll
  for (int d = 32; d; d >>= 1) {
    s1 += __shfl_xor(s1, d, 64);
    s2 += __shfl_xor(s2, d, 64);
  }
  __shared__ float r1[4], r2[4];
  int w = tid >> 6;
  if ((tid & 63) == 0) { r1[w] = s1; r2[w] = s2; }
  __syncthreads();
  if (tid == 0) {
    float S1 = r1[0]+r1[1]+r1[2]+r1[3];
    float S2 = r2[0]+r2[1]+r2[2]+r2[3];
    const float N = 1048576.0f;
    float mean = S1 / N;
    float var  = S2 / N - mean*mean;
    float inv  = rsqrtf(var + 1e-5f);
    float sc   = gamma[c] * inv;
    bn[c]      = sc;
    bn[32 + c] = beta[c] - mean*sc;
  }
}

// Final: BN affine (layer 3) + linear_out
__global__ __launch_bounds__(256) void k_out(
    const float* __restrict__ z, const float* __restrict__ bn,
    const float* __restrict__ w_out, const float* __restrict__ b_out,
    float* __restrict__ out)
{
  __shared__ float a[32];
  __shared__ float c0s;
  const int tid = threadIdx.x;
  if (tid < 32) a[tid] = bn[tid] * w_out[tid];
  if (tid == 0) {
    float t = b_out[0];
    for (int c = 0; c < 32; ++c) t += bn[32 + c] * w_out[c];
    c0s = t;
  }
  __syncthreads();
  int gid = blockIdx.x*256 + tid;             // [0, 262144)
  int b = gid >> 14, pos = (gid & 16383) << 2;
  const float* zb = z + (long)b*2097152 + pos;
  float c0 = c0s;
  float r0 = c0, r1 = c0, r2 = c0, r3 = c0;
  #pragma unroll 8
  for (int c = 0; c < 32; ++c) {
    float4 v = *(const float4*)(zb + c*65536);
    float ac = a[c];
    r0 += v.x*ac; r1 += v.y*ac; r2 += v.z*ac; r3 += v.w*ac;
  }
  float4 res; res.x = r0; res.y = r1; res.z = r2; res.w = r3;
  *(float4*)(out + (long)b*65536 + pos) = res;
}

extern "C" void kernel_launch(void* const* d_in, const int* in_sizes, int n_in,
                              void* d_out, int out_size, void* d_ws, size_t ws_size,
                              hipStream_t stream) {
  const float* x      = (const float*)d_in[0];
  const float* coords = (const float*)d_in[1];
  const float* w_in   = (const float*)d_in[2];
  const float* b_in   = (const float*)d_in[3];
  const float* w1r    = (const float*)d_in[4];
  const float* w1i    = (const float*)d_in[5];
  const float* w2r    = (const float*)d_in[6];
  const float* w2i    = (const float*)d_in[7];
  const float* lw     = (const float*)d_in[8];
  const float* lb     = (const float*)d_in[9];
  const float* gamma  = (const float*)d_in[10];
  const float* beta   = (const float*)d_in[11];
  const float* w_out  = (const float*)d_in[12];
  const float* b_out  = (const float*)d_in[13];
  float* out = (float*)d_out;
  float* ws  = (float*)d_ws;

  float* cs   = ws;
  float* z    = cs + 512;            // gx aliases z[0:3145728]
  float* gx   = z;
  float* wf   = z + 3145728;         // fused weights alias z[3.1M:5.5M]
  float* gy   = z + 33554432;
  float* fc   = gy + 3145728;        // part aliases fc
  float* fm   = fc + 294912;
  float* bn   = fm + 294912;
  float* part = fc;

  k_init<<<1, 256, 0, stream>>>(cs);
  k_prep<<<1152, 256, 0, stream>>>(w1r, w1i, w2r, w2i, lw, wf);
  k_embed_fwd<<<4096, 256, 0, stream>>>(x, coords, w_in, b_in, cs, gx);

  for (int l = 0; l < 4; ++l) {
    k_spec<<<192, 512, 0, stream>>>(gx, cs, (l == 0) ? nullptr : bn,
                                    wf + (long)l*589824, gy);
    k_fuse<<<4096, 256, 0, stream>>>(gy, cs, lb + l*32,
                                     (l < 3) ? gx : nullptr, part,
                                     (l == 3) ? z : nullptr);
    k_stats<<<32, 256, 0, stream>>>(part, gamma + l*32, beta + l*32, bn);
  }

  k_out<<<1024, 256, 0, stream>>>(z, bn, w_out, b_out, out);
}

// Round 14
// 538.232 us; speedup vs baseline: 1.6400x; 1.0056x over previous
//
#include <hip/hip_runtime.h>

constexpr double PI2 = 6.283185307179586476925286766559;
constexpr float INV_HW = 1.0f / 65536.0f;

// B=16, D=32, H=W=256, M=12, L=4
// ws (floats), total 37,290,560 (142.25 MiB — proven safe):
//   cs[512] | z[33554432] | gy[3145728] | fc-region[294912] | fm-region[294912] | bn[64]
//   gx ALIASES z[0:3145728]; wf ALIASES z[3145728:5505024];
//   part (262144) uses fc-region; Tg (3072) uses dead fm-region.
// gx layout: [b][y][ch32][mode24]; wf layout: [l][ky*12+kx][re1024|im1024].
// Tg layout: cos[12][128] | sin[12][128].

__global__ __launch_bounds__(256) void k_init(float* __restrict__ cs,
                                              float* __restrict__ Tg) {
  int t = threadIdx.x;
  double a = PI2 * (double)t / 256.0;
  cs[2*t]   = (float)cos(a);
  cs[2*t+1] = (float)sin(a);
  for (int i = t; i < 1536; i += 256) {
    int k = i >> 7, xs = i & 127;
    double ang = PI2 * (double)(k * xs) / 256.0;
    Tg[i]        = (float)cos(ang);
    Tg[1536 + i] = (float)sin(ang);
  }
}

// Fold residual pointwise linear (I + lw) into the spectral mix weights:
// W'[i][o] = w[i][o] + sum_c w[i][c] * lw[o][c]
__global__ __launch_bounds__(256) void k_prep(
    const float* __restrict__ w1r, const float* __restrict__ w1i,
    const float* __restrict__ w2r, const float* __restrict__ w2i,
    const float* __restrict__ lw, float* __restrict__ wf)
{
  const int bid = blockIdx.x;
  const int l = bid / 288, m = bid % 288;
  const int ky = m / 12, kx = m % 12;
  const int kyp = (ky < 12) ? ky : ky - 12;
  const float* wr_ = ((ky < 12) ? w1r : w2r) + l*147456;
  const float* wi_ = ((ky < 12) ? w1i : w2i) + l*147456;
  __shared__ float wre[1024], wim[1024], lwl[1024];
  const int tid = threadIdx.x;
  for (int f = tid; f < 1024; f += 256) {
    int idx = f*144 + kyp*12 + kx;
    wre[f] = wr_[idx]; wim[f] = wi_[idx];
    lwl[f] = lw[l*1024 + f];
  }
  __syncthreads();
  float* o_ = wf + (long)bid*2048;
  for (int f = tid; f < 1024; f += 256) {
    int i = f >> 5, o = f & 31;
    float ar = wre[f], ai = wim[f];
    #pragma unroll
    for (int c = 0; c < 32; ++c) {
      float lv = lwl[o*32 + c];
      ar += wre[i*32 + c] * lv;
      ai += wim[i*32 + c] * lv;
    }
    o_[f] = ar; o_[1024 + f] = ai;
  }
}

// Layer-0: h0 in registers -> x-DFT (even/odd real-input form) -> gx
__global__ __launch_bounds__(256) void k_embed_fwd(
    const float* __restrict__ xin, const float* __restrict__ coords,
    const float* __restrict__ w_in, const float* __restrict__ b_in,
    const float* __restrict__ cs, float* __restrict__ gxo)
{
  __shared__ float wl[96], bl[32];
  __shared__ __align__(16) float csl[512];
  __shared__ float S[32*257];
  const int tid = threadIdx.x;
  if (tid < 96) wl[tid] = w_in[tid];
  if (tid >= 96 && tid < 128) bl[tid-96] = b_in[tid-96];
  for (int f = tid; f < 512; f += 256) csl[f] = cs[f];
  const int b = blockIdx.x >> 8, y = blockIdx.x & 255;
  const float xv = xin[(b*256 + y)*256 + tid];
  const float c0 = coords[y*256 + tid];
  const float c1 = coords[65536 + y*256 + tid];
  __syncthreads();
  #pragma unroll 8
  for (int d = 0; d < 32; ++d)
    S[d*257 + tid] = wl[3*d]*xv + wl[3*d+1]*c0 + wl[3*d+2]*c1 + bl[d];
  __syncthreads();
  const int task = tid >> 5, o = tid & 31;
  if (task < 6) {
    const int kx0 = task*2, kx1 = kx0 + 1;   // kx0 even, kx1 odd
    const float* Sp = &S[o*257];
    const float s0v = Sp[0], s128 = Sp[128];
    float ar0 = s0v + s128, ai0 = 0.f;
    float ar1 = s0v - s128, ai1 = 0.f;
    int t0 = kx0, t1 = kx1;                  // angle index at x=1
    for (int xx = 1; xx < 128; ++xx) {
      float a = Sp[xx], bv = Sp[256 - xx];
      float e = a + bv, od = a - bv;
      float2 w0 = *(const float2*)&csl[2*t0];
      float2 w1 = *(const float2*)&csl[2*t1];
      ar0 += e*w0.x;  ai0 -= od*w0.y;
      ar1 += e*w1.x;  ai1 -= od*w1.y;
      t0 = (t0 + kx0) & 255;
      t1 = (t1 + kx1) & 255;
    }
    float4 w4; w4.x = ar0; w4.y = ai0; w4.z = ar1; w4.w = ai1;
    *(float4*)(gxo + ((long)(b*256 + y)*32 + o)*24 + task*4) = w4;
  }
}

// FUSED SPECTRAL: fwd-y DFT (mirror pairs) + channel mix + inv-y DFT
// (y-mirror pairs). block = (b,kx) XCD-swizzled, 512 threads.
__global__ __launch_bounds__(512) void k_spec(
    const float* __restrict__ gx, const float* __restrict__ cs,
    const float* __restrict__ bnp, const float* __restrict__ wfl,
    float* __restrict__ gy)
{
  const int bid = (blockIdx.x % 8) * 24 + blockIdx.x / 8;  // XCD swizzle (192=8*24)
  const int b = bid / 12, kx = bid % 12;
  __shared__ float2 Z[32*257];           // [ch][y], pad 257
  __shared__ float fcl[24*66];           // [ky][ch][2], row pad 66
  __shared__ float fml[24*66];           // [ky][o][2]
  __shared__ __align__(16) float csl[512];
  const int tid = threadIdx.x;
  if (tid < 512) csl[tid] = cs[tid];
  {
    const int ch = tid & 31;
    float sc = 1.0f, badd = 0.0f;
    if (bnp) { sc = bnp[ch]; if (kx == 0) badd = 256.0f * bnp[32 + ch]; }
    const float* src = gx + ((long)(b*256)*32 + ch)*24 + 2*kx;
    const int ybase = tid >> 5;          // 0..15
    #pragma unroll
    for (int i = 0; i < 16; ++i) {
      int y = ybase + 16*i;
      float2 v = *(const float2*)(src + (long)y*768);
      float2 w; w.x = sc*v.x + badd; w.y = sc*v.y;
      Z[ch*257 + y] = w;
    }
  }
  __syncthreads();
  // fwd_y: 832 half-tasks = 32ch x 13 mode-pairs x 2 y-halves
  for (int t = tid; t < 832; t += 512) {
    const int hf = t & 1, r = t >> 1;
    const int pr = r % 13, ch = r / 13;
    const int kyv = (pr <= 10) ? (pr + 1) : ((pr == 11) ? 0 : 244);
    const int y0 = hf << 7;
    int tt = (kyv * y0) & 255;
    float A = 0.f, Bv = 0.f, C2 = 0.f, D = 0.f;
    const float2* Zp = &Z[ch*257 + y0];
    for (int i = 0; i < 128; ++i) {
      float2 v = Zp[i];
      float2 w = *(const float2*)&csl[2*tt];
      A  += v.x*w.x;  D  += v.x*w.y;
      C2 += v.y*w.x;  Bv += v.y*w.y;
      tt = (tt + kyv) & 255;
    }
    A  += __shfl_xor(A, 1, 64);
    Bv += __shfl_xor(Bv, 1, 64);
    C2 += __shfl_xor(C2, 1, 64);
    D  += __shfl_xor(D, 1, 64);
    if (hf == 0) {
      const int slo = (pr <= 10) ? (pr + 1) : ((pr == 11) ? 0 : 12);
      fcl[slo*66 + 2*ch]     = A + Bv;
      fcl[slo*66 + 2*ch + 1] = C2 - D;
      if (pr <= 10) {
        fcl[(23 - pr)*66 + 2*ch]     = A - Bv;
        fcl[(23 - pr)*66 + 2*ch + 1] = C2 + D;
      }
    }
  }
  __syncthreads();
  for (int t = tid; t < 768; t += 512) {
    const int ky = t >> 5, o = t & 31;
    const float* wb = wfl + ((long)(ky*12 + kx))*2048;
    const float* fr = &fcl[ky*66];
    float ar = 0.f, ai = 0.f;
    #pragma unroll
    for (int i = 0; i < 32; ++i) {
      float fre = fr[2*i], fim = fr[2*i+1];
      float wr = wb[i*32 + o], wi = wb[1024 + i*32 + o];
      ar += fre*wr - fim*wi;
      ai += fre*wi + fim*wr;
    }
    fml[ky*66 + 2*o]     = ar;
    fml[ky*66 + 2*o + 1] = ai;
  }
  __syncthreads();
  {
    const int yp = tid & 127, og = tid >> 7;
    float tc[24], tsn[24];
    #pragma unroll
    for (int s = 0; s < 24; ++s) {
      int kyv = (s < 12) ? s : (232 + s);
      int tt = (kyv * yp) & 255;
      tc[s] = csl[2*tt]; tsn[s] = csl[2*tt+1];
    }
    const int yhi = (256 - yp) & 255;
    float* rowLo = gy + ((long)(b*256 + yp))*768 + kx*64;
    float* rowHi = gy + ((long)(b*256 + yhi))*768 + kx*64;
    #pragma unroll
    for (int oo = 0; oo < 8; oo += 2) {
      const int o = og*8 + oo;
      float A1a=0.f,A2a=0.f,A3a=0.f,A4a=0.f;
      float A1b=0.f,A2b=0.f,A3b=0.f,A4b=0.f;
      #pragma unroll
      for (int s = 0; s < 24; ++s) {
        float fra = fml[s*66 + 2*o],     fia = fml[s*66 + 2*o + 1];
        float frb = fml[s*66 + 2*o + 2], fib = fml[s*66 + 2*o + 3];
        float c = tc[s], sn = tsn[s];
        A1a += fra*c;  A2a += fia*sn;  A3a += fra*sn;  A4a += fia*c;
        A1b += frb*c;  A2b += fib*sn;  A3b += frb*sn;  A4b += fib*c;
      }
      float4 lo, hi;
      lo.x = (A1a - A2a)*INV_HW; lo.y = (A3a + A4a)*INV_HW;
      lo.z = (A1b - A2b)*INV_HW; lo.w = (A3b + A4b)*INV_HW;
      hi.x = (A1a + A2a)*INV_HW; hi.y = (A4a - A3a)*INV_HW;
      hi.z = (A1b + A2b)*INV_HW; hi.w = (A4b - A3b)*INV_HW;
      *(float4*)(rowLo + 2*o) = lo;
      *(float4*)(rowHi + 2*o) = hi;
    }
  }
  if (tid < 32) {
    const int o = tid;
    float re = 0.f, im = 0.f;
    #pragma unroll
    for (int s = 0; s < 24; ++s) {
      float fr = fml[s*66 + 2*o], fi = fml[s*66 + 2*o + 1];
      if (s & 1) { re -= fr; im -= fi; } else { re += fr; im += fi; }
    }
    float* row = gy + ((long)(b*256 + 128))*768 + kx*64;
    row[2*o]     = re*INV_HW;
    row[2*o + 1] = im*INV_HW;
  }
}

// FUSED: inverse-x c2r (x-mirror) + lb + relu + E/O decomposition in LDS
// + vectorized fwd-x DFT with mode-register accumulators + BN partials.
// Twiddle table T staged from global Tg; ai[0] == 0 exactly (real input).
__global__ __launch_bounds__(256) void k_fuse(
    const float* __restrict__ gy, const float* __restrict__ Tg,
    const float* __restrict__ lb,
    float* __restrict__ gxo, float* __restrict__ part, float* __restrict__ z)
{
  const int b = blockIdx.x >> 8, y = blockIdx.x & 255;
  const int tid = threadIdx.x;
  __shared__ __align__(16) float T[3168];   // cos[12][132] | sin[12][132] @1584
  __shared__ __align__(16) float E[32*132]; // E[ch][xs], xs 0..128
  __shared__ __align__(16) float O[32*132]; // O[ch][xs]; reused as red[]
  for (int i = tid; i < 1536; i += 256) {
    int k = i >> 7, xs0 = i & 127;
    T[k*132 + xs0]        = Tg[i];
    T[1584 + k*132 + xs0] = Tg[1536 + i];
  }
  __syncthreads();
  // ---- phase A: inv-x c2r, x-mirror pairs ----
  const int xs = tid & 127, half = tid >> 7;
  const int cbase = half << 4;
  const int xhi = (256 - xs) & 255;
  float tc[12], tsn[12];
  #pragma unroll
  for (int kx = 1; kx < 12; ++kx) {
    tc[kx]  = 2.0f * T[kx*132 + xs];
    tsn[kx] = 2.0f * T[1584 + kx*132 + xs];   // 0 at xs==0
  }
  const float* Gg = gy + (long)(b*256 + y)*768;   // wave-uniform base
  float zlo[16], zhi[16];
  #pragma unroll
  for (int cc = 0; cc < 16; cc += 2) {
    const int c = cbase + cc;
    float base0 = Gg[2*c], base1 = Gg[2*c + 2];
    float cos0 = 0.f, sin0 = 0.f, cos1 = 0.f, sin1 = 0.f;
    #pragma unroll
    for (int kx = 1; kx < 12; ++kx) {
      float4 g = *(const float4*)(Gg + kx*64 + 2*c);
      cos0 += g.x*tc[kx];  sin0 += g.y*tsn[kx];
      cos1 += g.z*tc[kx];  sin1 += g.w*tsn[kx];
    }
    const float l0 = lb[c], l1 = lb[c+1];
    zlo[cc]   = fmaxf(base0 + cos0 - sin0 + l0, 0.f);
    zhi[cc]   = fmaxf(base0 + cos0 + sin0 + l0, 0.f);
    zlo[cc+1] = fmaxf(base1 + cos1 - sin1 + l1, 0.f);
    zhi[cc+1] = fmaxf(base1 + cos1 + sin1 + l1, 0.f);
  }
  #pragma unroll
  for (int cc = 0; cc < 16; ++cc) {
    float e = (xs == 0) ? zlo[cc] : (zlo[cc] + zhi[cc]);
    float o = (xs == 0) ? 0.f     : (zlo[cc] - zhi[cc]);
    E[(cbase+cc)*132 + xs] = e;
    O[(cbase+cc)*132 + xs] = o;
  }
  if (z) {
    #pragma unroll
    for (int cc = 0; cc < 16; ++cc) {
      z[((b*32 + cbase+cc)*256 + y)*256 + xs]  = zlo[cc];
      z[((b*32 + cbase+cc)*256 + y)*256 + xhi] = zhi[cc];
    }
  }
  // x=128 fixup: lane = channel; sin terms vanish, cos = 2*(-1)^kx.
  if (tid < 32) {
    const int c = tid;
    float acc = Gg[2*c] + lb[c];
    #pragma unroll
    for (int kx = 1; kx < 12; ++kx) {
      float2 g = *(const float2*)(Gg + kx*64 + 2*c);
      acc += (kx & 1) ? (-2.0f * g.x) : (2.0f * g.x);
    }
    float zv = fmaxf(acc, 0.f);
    E[c*132 + 128] = zv;
    if (z) z[((b*32 + c)*256 + y)*256 + 128] = zv;
  }
  __syncthreads();
  // ---- phase B: lane (ch, seg) owns 16 xs, accumulates all 12 modes ----
  const int ch = tid & 31, seg = tid >> 5;
  float ar[12], ai[12], sq = 0.f;
  #pragma unroll
  for (int k = 0; k < 12; ++k) { ar[k] = 0.f; ai[k] = 0.f; }
  {
    const float* Erow = &E[ch*132 + seg*16];
    const float* Orow = &O[ch*132 + seg*16];
    if (gxo) {
      #pragma unroll
      for (int c4 = 0; c4 < 4; ++c4) {
        float4 E4 = *(const float4*)(Erow + 4*c4);
        float4 O4 = *(const float4*)(Orow + 4*c4);
        ar[0] += E4.x + E4.y + E4.z + E4.w;
        #pragma unroll
        for (int k = 1; k < 12; ++k) {
          float4 Tc4 = *(const float4*)&T[k*132 + seg*16 + 4*c4];
          float4 Ts4 = *(const float4*)&T[1584 + k*132 + seg*16 + 4*c4];
          ar[k] += E4.x*Tc4.x + E4.y*Tc4.y + E4.z*Tc4.z + E4.w*Tc4.w;
          ai[k] -= O4.x*Ts4.x + O4.y*Ts4.y + O4.z*Ts4.z + O4.w*Ts4.w;
        }
        sq += E4.x*E4.x + E4.y*E4.y + E4.z*E4.z + E4.w*E4.w
            + O4.x*O4.x + O4.y*O4.y + O4.z*O4.z + O4.w*O4.w;
      }
    } else {
      #pragma unroll
      for (int c4 = 0; c4 < 4; ++c4) {
        float4 E4 = *(const float4*)(Erow + 4*c4);
        float4 O4 = *(const float4*)(Orow + 4*c4);
        ar[0] += E4.x + E4.y + E4.z + E4.w;
        sq += E4.x*E4.x + E4.y*E4.y + E4.z*E4.z + E4.w*E4.w
            + O4.x*O4.x + O4.y*O4.y + O4.z*O4.z + O4.w*O4.w;
      }
    }
  }
  // seg-pair fold: lane ^ 32 is (ch, seg^1) within the same wave
  #pragma unroll
  for (int k = 0; k < 12; ++k) ar[k] += __shfl_xor(ar[k], 32, 64);
  #pragma unroll
  for (int k = 1; k < 12; ++k) ai[k] += __shfl_xor(ai[k], 32, 64);
  sq += __shfl_xor(sq, 32, 64);
  __syncthreads();                     // O reads done; safe to alias
  float* red = O;                      // red[w][ch][25] = 3200 <= 4224
  const int wv = tid >> 6;
  if ((tid & 63) < 32) {
    float* r = &red[(wv*32 + ch)*25];
    #pragma unroll
    for (int k = 0; k < 12; ++k) r[k] = ar[k];
    #pragma unroll
    for (int k = 1; k < 12; ++k) r[11 + k] = ai[k];
    r[23] = sq;
  }
  __syncthreads();
  // ---- final: (ch, q) handles 3 of 24 reduced values; endpoint fixups ----
  {
    const int q = tid >> 5;
    const float e0   = E[ch*132];
    const float e128 = E[ch*132 + 128];
    float* gp = gxo ? (gxo + ((long)(b*256 + y)*32 + ch)*24) : nullptr;
    #pragma unroll
    for (int j = 0; j < 3; ++j) {
      const int v = 3*q + j;
      float s = red[ch*25 + v]        + red[(32+ch)*25 + v]
              + red[(64+ch)*25 + v]   + red[(96+ch)*25 + v];
      if (v < 12) {
        s += (v & 1) ? -e128 : e128;   // + (-1)^k * S[128]
        if (gp) {
          gp[2*v] = s;
          if (v == 0) gp[1] = 0.f;     // Im X[0] = 0 for real input
        }
        if (v == 0) part[(long)blockIdx.x*64 + 2*ch] = s;   // BN sum
      } else if (v < 23) {
        if (gp) gp[2*(v - 11) + 1] = s;
      } else {
        // sumsq = sq_main/2 + S[0]^2/2 + S[128]^2
        part[(long)blockIdx.x*64 + 2*ch + 1] = 0.5f*s + 0.5f*e0*e0 + e128*e128;
      }
    }
  }
}

// Reduce partials -> BN scale/bias for next consumer
__global__ __launch_bounds__(256) void k_stats(
    const float* __restrict__ part, const float* __restrict__ gamma,
    const float* __restrict__ beta, float* __restrict__ bn)
{
  const int c = blockIdx.x, tid = threadIdx.x;
  float s1 = 0.f, s2 = 0.f;
  for (int j = tid; j < 4096; j += 256) {
    s1 += part[(long)j*64 + 2*c];
    s2 += part[(long)j*64 + 2*c + 1];
  }
  #pragma unroll
  for (int d = 32; d; d >>= 1) {
    s1 += __shfl_xor(s1, d, 64);
    s2 += __shfl_xor(s2, d, 64);
  }
  __shared__ float r1[4], r2[4];
  int w = tid >> 6;
  if ((tid & 63) == 0) { r1[w] = s1; r2[w] = s2; }
  __syncthreads();
  if (tid == 0) {
    float S1 = r1[0]+r1[1]+r1[2]+r1[3];
    float S2 = r2[0]+r2[1]+r2[2]+r2[3];
    const float N = 1048576.0f;
    float mean = S1 / N;
    float var  = S2 / N - mean*mean;
    float inv  = rsqrtf(var + 1e-5f);
    float sc   = gamma[c] * inv;
    bn[c]      = sc;
    bn[32 + c] = beta[c] - mean*sc;
  }
}

// Final: BN affine (layer 3) + linear_out
__global__ __launch_bounds__(256) void k_out(
    const float* __restrict__ z, const float* __restrict__ bn,
    const float* __restrict__ w_out, const float* __restrict__ b_out,
    float* __restrict__ out)
{
  __shared__ float a[32];
  __shared__ float c0s;
  const int tid = threadIdx.x;
  if (tid < 32) a[tid] = bn[tid] * w_out[tid];
  if (tid == 0) {
    float t = b_out[0];
    for (int c = 0; c < 32; ++c) t += bn[32 + c] * w_out[c];
    c0s = t;
  }
  __syncthreads();
  int gid = blockIdx.x*256 + tid;             // [0, 262144)
  int b = gid >> 14, pos = (gid & 16383) << 2;
  const float* zb = z + (long)b*2097152 + pos;
  float c0 = c0s;
  float r0 = c0, r1 = c0, r2 = c0, r3 = c0;
  #pragma unroll 8
  for (int c = 0; c < 32; ++c) {
    float4 v = *(const float4*)(zb + c*65536);
    float ac = a[c];
    r0 += v.x*ac; r1 += v.y*ac; r2 += v.z*ac; r3 += v.w*ac;
  }
  float4 res; res.x = r0; res.y = r1; res.z = r2; res.w = r3;
  *(float4*)(out + (long)b*65536 + pos) = res;
}

extern "C" void kernel_launch(void* const* d_in, const int* in_sizes, int n_in,
                              void* d_out, int out_size, void* d_ws, size_t ws_size,
                              hipStream_t stream) {
  const float* x      = (const float*)d_in[0];
  const float* coords = (const float*)d_in[1];
  const float* w_in   = (const float*)d_in[2];
  const float* b_in   = (const float*)d_in[3];
  const float* w1r    = (const float*)d_in[4];
  const float* w1i    = (const float*)d_in[5];
  const float* w2r    = (const float*)d_in[6];
  const float* w2i    = (const float*)d_in[7];
  const float* lw     = (const float*)d_in[8];
  const float* lb     = (const float*)d_in[9];
  const float* gamma  = (const float*)d_in[10];
  const float* beta   = (const float*)d_in[11];
  const float* w_out  = (const float*)d_in[12];
  const float* b_out  = (const float*)d_in[13];
  float* out = (float*)d_out;
  float* ws  = (float*)d_ws;

  float* cs   = ws;
  float* z    = cs + 512;            // gx aliases z[0:3145728]
  float* gx   = z;
  float* wf   = z + 3145728;         // fused weights alias z[3.1M:5.5M]
  float* gy   = z + 33554432;
  float* part = gy + 3145728;        // old fc region (uses 262144 of 294912)
  float* Tg   = part + 294912;       // old fm region (uses 3072 of 294912)
  float* bn   = Tg + 294912;

  k_init<<<1, 256, 0, stream>>>(cs, Tg);
  k_prep<<<1152, 256, 0, stream>>>(w1r, w1i, w2r, w2i, lw, wf);
  k_embed_fwd<<<4096, 256, 0, stream>>>(x, coords, w_in, b_in, cs, gx);

  for (int l = 0; l < 4; ++l) {
    k_spec<<<192, 512, 0, stream>>>(gx, cs, (l == 0) ? nullptr : bn,
                                    wf + (long)l*589824, gy);
    k_fuse<<<4096, 256, 0, stream>>>(gy, Tg, lb + l*32,
                                     (l < 3) ? gx : nullptr, part,
                                     (l == 3) ? z : nullptr);
    k_stats<<<32, 256, 0, stream>>>(part, gamma + l*32, beta + l*32, bn);
  }

  k_out<<<1024, 256, 0, stream>>>(z, bn, w_out, b_out, out);
}